// Round 1
// baseline (1879.991 us; speedup 1.0000x reference)
//
#include <hip/hip_runtime.h>
#include <math.h>

#define NT 88200        // T
#define NB 8            // batch
#define TC 1378         // T // 64
#define KC 1023         // composite FIR taps

static constexpr float IN_GAIN_F = 1.8197008586099834f; // 10^(5.2/20)

// ---- workspace layout (float offsets) ----
#define OFF_W     0            // composite flipped weights, 3 x 1024 (pad tap = 0)
#define OFF_WT0   3072         // reordered conv weights [k][ic][oc]
#define OFF_WT1   3456
#define OFF_WT2   15744
#define OFF_WT3   28032
#define OFF_WT4   40320
#define OFF_BANDS 40960        // [B][3][C][T] = 4233600
#define OFF_XRMS  4274560      // [24][TC]
#define OFF_ENV   4307632      // [24][TC]
#define OFF_COMB  4340704      // [B][C][T] = 1411200
// total ~5.76M floats = 23 MB

__device__ __forceinline__ float geluf(float x) {
  return 0.5f * x * (1.f + erff(x * 0.7071067811865476f));
}

// ---------------------------------------------------------------- prep
// task 0: composite FIR weights (flipped-domain convolution of flipped IRs)
// task 1..5: reorder conv weights w[oc][ic][k] -> wT[k][ic][oc]
__global__ __launch_bounds__(256) void k_prep(
    const float* __restrict__ irLL, const float* __restrict__ irLH,
    const float* __restrict__ irHL, const float* __restrict__ irHH,
    const float* __restrict__ w0, const float* __restrict__ w1,
    const float* __restrict__ w2, const float* __restrict__ w3,
    const float* __restrict__ w4, float* __restrict__ ws)
{
  int gid = blockIdx.x * 256 + threadIdx.x;
  int task = blockIdx.y;
  if (task == 0) {
    if (gid >= 3072) return;
    int band = gid >> 10, j = gid & 1023;
    float v = 0.f;
    if (j < 1023) {
      if (band == 2) {                      // low: 512-tap, right-aligned
        v = (j >= 511) ? irLL[j - 511] : 0.f;
      } else {                              // high/mid: conv(irLH, irH?)
        const float* wb = (band == 0) ? irHH : irHL;
        int lo = j - 511; if (lo < 0) lo = 0;
        int hi = (j < 511) ? j : 511;
        float acc = 0.f;
        for (int i = lo; i <= hi; ++i) acc += irLH[i] * wb[j - i];
        v = acc;
      }
    }
    ws[OFF_W + gid] = v;
  } else {
    int l = task - 1;
    const int cins[5]  = {2, 64, 64, 64, 64};
    const int couts[5] = {64, 64, 64, 64, 2};
    const float* wsrc[5] = {w0, w1, w2, w3, w4};
    const int dsts[5] = {OFF_WT0, OFF_WT1, OFF_WT2, OFF_WT3, OFF_WT4};
    int cin = cins[l], cout = couts[l];
    int n = 3 * cin * cout;
    if (gid >= n) return;
    int k = gid / (cin * cout);
    int rem = gid - k * cin * cout;
    int ic = rem / cout;
    int oc = rem - ic * cout;
    ws[dsts[l] + gid] = wsrc[l][(oc * cin + ic) * 3 + k];
  }
}

// ---------------------------------------------------------------- band FIR
// y[n] = sum_j W[j] * xpad[n+j], xpad left-padded by 1022. 4 outputs/thread.
__global__ __launch_bounds__(256) void k_fir(const float* __restrict__ audio,
                                             float* __restrict__ ws)
{
  __shared__ float xs[2048];
  __shared__ float wl[3][1024];
  int bc = blockIdx.x;               // b*2 + c
  int t0 = blockIdx.y * 1024;
  int tid = threadIdx.x;
  const float* Wc = ws + OFF_W;
  for (int i = tid; i < 3072; i += 256) wl[i >> 10][i & 1023] = Wc[i];
  const float* x = audio + bc * NT;
  for (int i = tid; i < 2048; i += 256) {
    int g = t0 - 1022 + i;
    xs[i] = (g >= 0 && g < NT) ? x[g] * IN_GAIN_F : 0.f;
  }
  __syncthreads();

  int base = tid * 4;
  float a0[4] = {0,0,0,0}, a1[4] = {0,0,0,0}, a2[4] = {0,0,0,0};
  float4 xv0 = *reinterpret_cast<const float4*>(&xs[base]);
  int j = 0;
  for (; j < 508; j += 4) {          // low band has zero taps here
    float4 xv1 = *reinterpret_cast<const float4*>(&xs[base + j + 4]);
    float xw[8] = {xv0.x, xv0.y, xv0.z, xv0.w, xv1.x, xv1.y, xv1.z, xv1.w};
    float4 w0v = *reinterpret_cast<const float4*>(&wl[0][j]);
    float4 w1v = *reinterpret_cast<const float4*>(&wl[1][j]);
#pragma unroll
    for (int r = 0; r < 4; ++r) {
      a0[r] += w0v.x*xw[r] + w0v.y*xw[r+1] + w0v.z*xw[r+2] + w0v.w*xw[r+3];
      a1[r] += w1v.x*xw[r] + w1v.y*xw[r+1] + w1v.z*xw[r+2] + w1v.w*xw[r+3];
    }
    xv0 = xv1;
  }
  for (; j < 1024; j += 4) {
    float4 xv1 = *reinterpret_cast<const float4*>(&xs[base + j + 4]);
    float xw[8] = {xv0.x, xv0.y, xv0.z, xv0.w, xv1.x, xv1.y, xv1.z, xv1.w};
    float4 w0v = *reinterpret_cast<const float4*>(&wl[0][j]);
    float4 w1v = *reinterpret_cast<const float4*>(&wl[1][j]);
    float4 w2v = *reinterpret_cast<const float4*>(&wl[2][j]);
#pragma unroll
    for (int r = 0; r < 4; ++r) {
      a0[r] += w0v.x*xw[r] + w0v.y*xw[r+1] + w0v.z*xw[r+2] + w0v.w*xw[r+3];
      a1[r] += w1v.x*xw[r] + w1v.y*xw[r+1] + w1v.z*xw[r+2] + w1v.w*xw[r+3];
      a2[r] += w2v.x*xw[r] + w2v.y*xw[r+1] + w2v.z*xw[r+2] + w2v.w*xw[r+3];
    }
    xv0 = xv1;
  }
  int b = bc >> 1, c = bc & 1;
  int t = t0 + base;
  if (t < NT) {
    float* bands = ws + OFF_BANDS;
    *reinterpret_cast<float4*>(&bands[((b*3+0)*2 + c)*NT + t]) = make_float4(a0[0],a0[1],a0[2],a0[3]);
    *reinterpret_cast<float4*>(&bands[((b*3+1)*2 + c)*NT + t]) = make_float4(a1[0],a1[1],a1[2],a1[3]);
    *reinterpret_cast<float4*>(&bands[((b*3+2)*2 + c)*NT + t]) = make_float4(a2[0],a2[1],a2[2],a2[3]);
  }
}

// ---------------------------------------------------------------- block RMS
__global__ __launch_bounds__(64) void k_rms(float* __restrict__ ws)
{
  int row = blockIdx.x;                      // b*3 + band, 0..23
  int j = blockIdx.y * 64 + threadIdx.x;     // rms-block index
  if (j >= TC) return;
  const float* bnd = ws + OFF_BANDS;
  const float* p0 = bnd + (row*2 + 0)*NT + j*64;
  const float* p1 = bnd + (row*2 + 1)*NT + j*64;
  float acc = 0.f;
#pragma unroll
  for (int s = 0; s < 64; s += 4) {
    float4 a = *reinterpret_cast<const float4*>(&p0[s]);
    float4 c = *reinterpret_cast<const float4*>(&p1[s]);
    acc += a.x*a.x + a.y*a.y + a.z*a.z + a.w*a.w
         + c.x*c.x + c.y*c.y + c.z*c.z + c.w*c.w;
  }
  ws[OFF_XRMS + row*TC + j] = sqrtf(acc * (0.5f/64.f) + 1e-7f);
}

// ---------------------------------------------------------------- decaying-max scan
// env[t] = max_{s<=t} x[s] * k^(t-s), Hillis-Steele with decay-weighted max
__global__ __launch_bounds__(256) void k_scan(const float* __restrict__ rel_alphas,
                                              float* __restrict__ ws)
{
  __shared__ float sA[TC], sB[TC];
  int row = blockIdx.x;
  int tid = threadIdx.x;
  float kdec = 1.f - rel_alphas[row >> 3];   // reproduces reference's repeat() indexing
  const float* xr = ws + OFF_XRMS + row*TC;
  for (int i = tid; i < TC; i += 256) sA[i] = xr[i];
  __syncthreads();
  float* in = sA; float* outp = sB;
  for (int off = 1; off < 2048; off <<= 1) {
    float kp = powf(kdec, (float)off);
    for (int i = tid; i < TC; i += 256) {
      float v = in[i];
      if (i >= off) v = fmaxf(v, in[i-off] * kp);
      outp[i] = v;
    }
    __syncthreads();
    float* tmp = in; in = outp; outp = tmp;
  }
  float* env = ws + OFF_ENV + row*TC;
  for (int i = tid; i < TC; i += 256) env[i] = in[i];
}

// ---------------------------------------------------------------- gain + combine
__global__ __launch_bounds__(256) void k_gain(const float* __restrict__ params,
                                              const float* __restrict__ kneep,
                                              float* __restrict__ ws)
{
  int b = blockIdx.x;
  int t = blockIdx.y * 256 + threadIdx.x;
  if (t >= NT) return;
  const float* bands = ws + OFF_BANDS;
  const float* env = ws + OFF_ENV;
  float knee = kneep[0];
  float halfk = 0.5f * knee;
  float inv2k = 1.f / (2.f * knee);
  const float scale = (float)(1377.0 / 88199.0);
  float pos = (float)t * scale;
  int i0 = (int)floorf(pos);
  i0 = i0 < 0 ? 0 : (i0 > TC - 2 ? TC - 2 : i0);
  float frac = pos - (float)i0;
  const int tacol[3] = {3, 2, 1};
  const int tbcol[3] = {6, 5, 4};
  const float asl[3] = {1.f, (float)(1.0 - 1.0/66.7), (float)(1.0 - 1.0/66.7)};
  const float bsl = (float)(1.0 - 1.0/4.17);
  const float og[3] = {10.3f, 5.7f, 10.3f};
  float c0 = 0.f, c1 = 0.f;
#pragma unroll
  for (int band = 0; band < 3; ++band) {
    int row = b*3 + band;
    float e = env[row*TC + i0] * (1.f - frac) + env[row*TC + i0 + 1] * frac;
    float edb = 20.f * log10f(e + 1e-7f);
    float ta = params[b*7 + tacol[band]];
    float tb = params[b*7 + tbcol[band]];
    float d1 = edb - ta;
    float gk1 = asl[band] * (d1 + halfk) * (d1 + halfk) * inv2k;
    float ka = (fabsf(d1) <= halfk) ? gk1 : (d1 > halfk ? asl[band]*d1 : 0.f);
    float d2 = tb - edb;                     // (-edb) - (-tb)
    float gk2 = bsl * (d2 + halfk) * (d2 + halfk) * inv2k;
    float kb = (fabsf(d2) <= halfk) ? gk2 : (d2 > halfk ? bsl*d2 : 0.f);
    float gdb = -ka + kb + og[band];
    gdb = fminf(fmaxf(gdb, -80.f), 40.f);
    float g = exp2f(gdb * 0.16609640474436812f);   // 10^(gdb/20)
    c0 += bands[(row*2 + 0)*NT + t] * g;
    c1 += bands[(row*2 + 1)*NT + t] * g;
  }
  float* comb = ws + OFF_COMB;
  comb[(b*2 + 0)*NT + t] = c0;
  comb[(b*2 + 1)*NT + t] = c1;
}

// ---------------------------------------------------------------- fused dilated conv net
// tile of 64 output samples per block; halo 16 each side; ping-pong LDS buffers.
// buffers anchored at time t0-16 (index p <-> t0-16+p), spans:
// cmb [0,96), r0 [1,95), r1 [3,93), r2 [7,89), r3 [15,81), res [16,80)
__device__ __forceinline__ void layer64(const float (*in)[96], float (*outb)[96],
    const float* __restrict__ w, const float* __restrict__ bias,
    int d, int plo, int phi, int tx, int ty, int t0)
{
  int ocb = ty * 8;
  float acc[3][8];
#pragma unroll
  for (int c = 0; c < 3; ++c)
#pragma unroll
    for (int o = 0; o < 8; ++o) acc[c][o] = bias[ocb + o];
  int q[3];
#pragma unroll
  for (int c = 0; c < 3; ++c) {
    int p = plo + c*32 + tx;
    q[c] = p < (phi - 1) ? p : (phi - 1);   // clamp: keeps LDS reads in valid span
  }
  for (int ic = 0; ic < 64; ++ic) {
    float xk[3][3];
#pragma unroll
    for (int c = 0; c < 3; ++c) {
      xk[0][c] = in[ic][q[c] - d];
      xk[1][c] = in[ic][q[c]];
      xk[2][c] = in[ic][q[c] + d];
    }
#pragma unroll
    for (int k = 0; k < 3; ++k) {
      float4 wa = *reinterpret_cast<const float4*>(&w[(k*64 + ic)*64 + ocb]);
      float4 wb = *reinterpret_cast<const float4*>(&w[(k*64 + ic)*64 + ocb + 4]);
#pragma unroll
      for (int c = 0; c < 3; ++c) {
        float xv = xk[k][c];
        acc[c][0] += wa.x*xv; acc[c][1] += wa.y*xv; acc[c][2] += wa.z*xv; acc[c][3] += wa.w*xv;
        acc[c][4] += wb.x*xv; acc[c][5] += wb.y*xv; acc[c][6] += wb.z*xv; acc[c][7] += wb.w*xv;
      }
    }
  }
#pragma unroll
  for (int c = 0; c < 3; ++c) {
    int p = plo + c*32 + tx;
    if (p < phi) {
      int t = t0 - 16 + p;
      bool z = (t < 0) | (t >= NT);         // zero outside signal: matches zero padding
#pragma unroll
      for (int o = 0; o < 8; ++o)
        outb[ocb + o][p] = z ? 0.f : geluf(acc[c][o]);
    }
  }
}

__global__ __launch_bounds__(256) void k_convnet(
    const float* __restrict__ audio, const float* __restrict__ params,
    const float* __restrict__ b0, const float* __restrict__ b1,
    const float* __restrict__ b2, const float* __restrict__ b3,
    const float* __restrict__ b4, const float* __restrict__ ws,
    float* __restrict__ out)
{
  __shared__ float cmb[2][96];
  __shared__ float bufA[64][96];
  __shared__ float bufB[64][96];
  int tile = blockIdx.x, b = blockIdx.y;
  int t0 = tile * 64;
  int tx = threadIdx.x, ty = threadIdx.y;
  int tid = ty * 32 + tx;
  const float* comb = ws + OFF_COMB;
  for (int i = tid; i < 192; i += 256) {
    int ic = i / 96, p = i - ic * 96;
    int t = t0 - 16 + p;
    cmb[ic][p] = (t >= 0 && t < NT) ? comb[(b*2 + ic)*NT + t] : 0.f;
  }
  __syncthreads();

  int ocb = ty * 8;
  // ---- L0: cin=2, d=1, span [1,95)
  {
    const float* w = ws + OFF_WT0;
    float acc[3][8];
#pragma unroll
    for (int c = 0; c < 3; ++c)
#pragma unroll
      for (int o = 0; o < 8; ++o) acc[c][o] = b0[ocb + o];
#pragma unroll
    for (int ic = 0; ic < 2; ++ic) {
      float xk[3][3];
#pragma unroll
      for (int c = 0; c < 3; ++c) {
        int p = 1 + c*32 + tx;
        int q = p < 94 ? p : 94;
        xk[0][c] = cmb[ic][q - 1]; xk[1][c] = cmb[ic][q]; xk[2][c] = cmb[ic][q + 1];
      }
#pragma unroll
      for (int k = 0; k < 3; ++k) {
        float4 wa = *reinterpret_cast<const float4*>(&w[(k*2 + ic)*64 + ocb]);
        float4 wb = *reinterpret_cast<const float4*>(&w[(k*2 + ic)*64 + ocb + 4]);
#pragma unroll
        for (int c = 0; c < 3; ++c) {
          float xv = xk[k][c];
          acc[c][0] += wa.x*xv; acc[c][1] += wa.y*xv; acc[c][2] += wa.z*xv; acc[c][3] += wa.w*xv;
          acc[c][4] += wb.x*xv; acc[c][5] += wb.y*xv; acc[c][6] += wb.z*xv; acc[c][7] += wb.w*xv;
        }
      }
    }
#pragma unroll
    for (int c = 0; c < 3; ++c) {
      int p = 1 + c*32 + tx;
      if (p < 95) {
        int t = t0 - 16 + p;
        bool z = (t < 0) | (t >= NT);
#pragma unroll
        for (int o = 0; o < 8; ++o)
          bufA[ocb + o][p] = z ? 0.f : geluf(acc[c][o]);
      }
    }
  }
  __syncthreads();
  layer64(bufA, bufB, ws + OFF_WT1, b1, 2, 3, 93, tx, ty, t0);
  __syncthreads();
  layer64(bufB, bufA, ws + OFF_WT2, b2, 4, 7, 89, tx, ty, t0);
  __syncthreads();
  layer64(bufA, bufB, ws + OFF_WT3, b3, 8, 15, 81, tx, ty, t0);
  __syncthreads();

  // ---- L4: cin=64, cout=2, d=1, span [16,80) + final mix
  if (ty < 2) {
    const float* w = ws + OFF_WT4;
    float r[2] = {b4[ty], b4[ty]};
    for (int ic = 0; ic < 64; ++ic) {
      float x0[2], x1[2], x2[2];
#pragma unroll
      for (int c = 0; c < 2; ++c) {
        int p = 16 + c*32 + tx;
        x0[c] = bufB[ic][p - 1]; x1[c] = bufB[ic][p]; x2[c] = bufB[ic][p + 1];
      }
      float wv0 = w[(0*64 + ic)*2 + ty];
      float wv1 = w[(1*64 + ic)*2 + ty];
      float wv2 = w[(2*64 + ic)*2 + ty];
#pragma unroll
      for (int c = 0; c < 2; ++c)
        r[c] += wv0*x0[c] + wv1*x1[c] + wv2*x2[c];
    }
    float amt = params[b*7];
#pragma unroll
    for (int c = 0; c < 2; ++c) {
      int t = t0 + c*32 + tx;
      if (t < NT) {
        float a = audio[(b*2 + ty)*NT + t];
        out[(b*2 + ty)*NT + t] = (1.f - amt)*a + amt*(cmb[ty][16 + c*32 + tx] + r[c]);
      }
    }
  }
}

// ----------------------------------------------------------------
extern "C" void kernel_launch(void* const* d_in, const int* in_sizes, int n_in,
                              void* d_out, int out_size, void* d_ws, size_t ws_size,
                              hipStream_t stream)
{
  (void)in_sizes; (void)n_in; (void)out_size; (void)ws_size;
  const float* audio = (const float*)d_in[0];
  const float* params = (const float*)d_in[1];
  const float* rel   = (const float*)d_in[2];
  const float* knee  = (const float*)d_in[3];
  const float* irLL  = (const float*)d_in[4];
  const float* irLH  = (const float*)d_in[5];
  const float* irHL  = (const float*)d_in[6];
  const float* irHH  = (const float*)d_in[7];
  const float* w0 = (const float*)d_in[8];  const float* b0 = (const float*)d_in[9];
  const float* w1 = (const float*)d_in[10]; const float* b1 = (const float*)d_in[11];
  const float* w2 = (const float*)d_in[12]; const float* b2 = (const float*)d_in[13];
  const float* w3 = (const float*)d_in[14]; const float* b3 = (const float*)d_in[15];
  const float* w4 = (const float*)d_in[16]; const float* b4 = (const float*)d_in[17];
  float* out = (float*)d_out;
  float* ws  = (float*)d_ws;

  hipLaunchKernelGGL(k_prep, dim3(48, 6), dim3(256), 0, stream,
                     irLL, irLH, irHL, irHH, w0, w1, w2, w3, w4, ws);
  hipLaunchKernelGGL(k_fir, dim3(16, 87), dim3(256), 0, stream, audio, ws);
  hipLaunchKernelGGL(k_rms, dim3(24, 22), dim3(64), 0, stream, ws);
  hipLaunchKernelGGL(k_scan, dim3(24), dim3(256), 0, stream, rel, ws);
  hipLaunchKernelGGL(k_gain, dim3(8, 345), dim3(256), 0, stream, params, knee, ws);
  hipLaunchKernelGGL(k_convnet, dim3(1379, 8), dim3(32, 8), 0, stream,
                     audio, params, b0, b1, b2, b3, b4, ws, out);
}

// Round 2
// 611.968 us; speedup vs baseline: 3.0720x; 3.0720x over previous
//
#include <hip/hip_runtime.h>
#include <math.h>

#define NT 88200        // T
#define NB 8            // batch
#define TC 1378         // T // 64

static constexpr float IN_GAIN_F = 1.8197008586099834f; // 10^(5.2/20)

// ---- workspace layout (float offsets) ----
#define OFF_W     0            // composite flipped FIR weights, 3 x 1024
#define OFF_WT0   3072         // L0 weights [k][ic][oc] fp32 (384)
#define OFF_W4F   3456         // L4 weights [ch][k][ic] fp32 (384)
#define OFF_ABF   3840         // MFMA A-frag bf16 packs, 3 layers x 12288 shorts
#define OFF_BANDS 22272        // [B][3][C][T] = 4233600
#define OFF_XRMS  4255872      // [24][TC]
#define OFF_ENV   4288944      // [24][TC]
#define OFF_COMB  4322016      // [B][C][T] = 1411200
// total 5733216 floats = 22.9 MB

typedef __attribute__((ext_vector_type(8))) short short8v;
typedef __attribute__((ext_vector_type(4))) short short4v;
typedef __attribute__((ext_vector_type(4))) float float4v;

__device__ __forceinline__ float geluf(float x) {
  return 0.5f * x * (1.f + erff(x * 0.7071067811865476f));
}
__device__ __forceinline__ short f2bf(float x) {
  unsigned int u = __float_as_uint(x);
  u += 0x7fffu + ((u >> 16) & 1u);        // RNE
  return (short)(u >> 16);
}
__device__ __forceinline__ float bf2f(short s) {
  return __uint_as_float(((unsigned int)(unsigned short)s) << 16);
}

// ---------------------------------------------------------------- prep
// task 0: composite FIR weights; task 1: L0 reorder; task 2: L4 reorder;
// tasks 3..5: MFMA A-fragment packing for w1..w3 (bf16).
__global__ __launch_bounds__(256) void k_prep(
    const float* __restrict__ irLL, const float* __restrict__ irLH,
    const float* __restrict__ irHL, const float* __restrict__ irHH,
    const float* __restrict__ w0, const float* __restrict__ w1,
    const float* __restrict__ w2, const float* __restrict__ w3,
    const float* __restrict__ w4, float* __restrict__ ws)
{
  int gid = blockIdx.x * 256 + threadIdx.x;
  int task = blockIdx.y;
  if (task == 0) {
    if (gid >= 3072) return;
    int band = gid >> 10, j = gid & 1023;
    float v = 0.f;
    if (j < 1023) {
      if (band == 2) {                      // low: 512-tap, right-aligned
        v = (j >= 511) ? irLL[j - 511] : 0.f;
      } else {                              // high/mid: conv(irLH, irH?)
        const float* wb = (band == 0) ? irHH : irHL;
        int lo = j - 511; if (lo < 0) lo = 0;
        int hi = (j < 511) ? j : 511;
        float acc = 0.f;
        for (int i = lo; i <= hi; ++i) acc += irLH[i] * wb[j - i];
        v = acc;
      }
    }
    ws[OFF_W + gid] = v;
  } else if (task == 1) {                   // wT0[k][ic][oc], cin=2
    if (gid >= 384) return;
    int k = gid / 128, rem = gid - k * 128;
    int ic = rem >> 6, oc = rem & 63;
    ws[OFF_WT0 + gid] = w0[(oc * 2 + ic) * 3 + k];
  } else if (task == 2) {                   // w4f[ch][k][ic]
    if (gid >= 384) return;
    int ch = gid / 192, rem = gid - ch * 192;
    int k = rem >> 6, ic = rem & 63;
    ws[OFF_W4F + gid] = w4[(ch * 64 + ic) * 3 + k];
  } else {                                  // A-pack layer l (w1..w3)
    int l = task - 3;
    if (gid >= 12288) return;
    const float* wl = (l == 0) ? w1 : (l == 1) ? w2 : w3;
    int wm = gid / 3072;
    int rem = gid - wm * 3072;
    int s = rem / 512;
    int rem2 = rem - s * 512;
    int lane = rem2 >> 3;
    int j = gid & 7;
    int m = wm * 16 + (lane & 15);               // oc
    int kk = s * 32 + ((lane >> 4) << 3) + j;    // flattened K = k*64+ic
    int k = kk >> 6, ic = kk & 63;
    short* ap = (short*)(ws + OFF_ABF);
    ap[l * 12288 + gid] = f2bf(wl[(m * 64 + ic) * 3 + k]);
  }
}

// ---------------------------------------------------------------- band FIR
__global__ __launch_bounds__(256) void k_fir(const float* __restrict__ audio,
                                             float* __restrict__ ws)
{
  __shared__ float xs[2048];
  __shared__ float wl[3][1024];
  int bc = blockIdx.x;               // b*2 + c
  int t0 = blockIdx.y * 1024;
  int tid = threadIdx.x;
  const float* Wc = ws + OFF_W;
  for (int i = tid; i < 3072; i += 256) wl[i >> 10][i & 1023] = Wc[i];
  const float* x = audio + bc * NT;
  for (int i = tid; i < 2048; i += 256) {
    int g = t0 - 1022 + i;
    xs[i] = (g >= 0 && g < NT) ? x[g] * IN_GAIN_F : 0.f;
  }
  __syncthreads();

  int base = tid * 4;
  float a0[4] = {0,0,0,0}, a1[4] = {0,0,0,0}, a2[4] = {0,0,0,0};
  float4 xv0 = *reinterpret_cast<const float4*>(&xs[base]);
  int j = 0;
  for (; j < 508; j += 4) {          // low band has zero taps here
    float4 xv1 = *reinterpret_cast<const float4*>(&xs[base + j + 4]);
    float xw[8] = {xv0.x, xv0.y, xv0.z, xv0.w, xv1.x, xv1.y, xv1.z, xv1.w};
    float4 w0v = *reinterpret_cast<const float4*>(&wl[0][j]);
    float4 w1v = *reinterpret_cast<const float4*>(&wl[1][j]);
#pragma unroll
    for (int r = 0; r < 4; ++r) {
      a0[r] += w0v.x*xw[r] + w0v.y*xw[r+1] + w0v.z*xw[r+2] + w0v.w*xw[r+3];
      a1[r] += w1v.x*xw[r] + w1v.y*xw[r+1] + w1v.z*xw[r+2] + w1v.w*xw[r+3];
    }
    xv0 = xv1;
  }
  for (; j < 1024; j += 4) {
    float4 xv1 = *reinterpret_cast<const float4*>(&xs[base + j + 4]);
    float xw[8] = {xv0.x, xv0.y, xv0.z, xv0.w, xv1.x, xv1.y, xv1.z, xv1.w};
    float4 w0v = *reinterpret_cast<const float4*>(&wl[0][j]);
    float4 w1v = *reinterpret_cast<const float4*>(&wl[1][j]);
    float4 w2v = *reinterpret_cast<const float4*>(&wl[2][j]);
#pragma unroll
    for (int r = 0; r < 4; ++r) {
      a0[r] += w0v.x*xw[r] + w0v.y*xw[r+1] + w0v.z*xw[r+2] + w0v.w*xw[r+3];
      a1[r] += w1v.x*xw[r] + w1v.y*xw[r+1] + w1v.z*xw[r+2] + w1v.w*xw[r+3];
      a2[r] += w2v.x*xw[r] + w2v.y*xw[r+1] + w2v.z*xw[r+2] + w2v.w*xw[r+3];
    }
    xv0 = xv1;
  }
  int b = bc >> 1, c = bc & 1;
  int t = t0 + base;
  if (t < NT) {
    float* bands = ws + OFF_BANDS;
    *reinterpret_cast<float4*>(&bands[((b*3+0)*2 + c)*NT + t]) = make_float4(a0[0],a0[1],a0[2],a0[3]);
    *reinterpret_cast<float4*>(&bands[((b*3+1)*2 + c)*NT + t]) = make_float4(a1[0],a1[1],a1[2],a1[3]);
    *reinterpret_cast<float4*>(&bands[((b*3+2)*2 + c)*NT + t]) = make_float4(a2[0],a2[1],a2[2],a2[3]);
  }
}

// ---------------------------------------------------------------- block RMS
__global__ __launch_bounds__(64) void k_rms(float* __restrict__ ws)
{
  int row = blockIdx.x;                      // b*3 + band
  int j = blockIdx.y * 64 + threadIdx.x;
  if (j >= TC) return;
  const float* bnd = ws + OFF_BANDS;
  const float* p0 = bnd + (row*2 + 0)*NT + j*64;
  const float* p1 = bnd + (row*2 + 1)*NT + j*64;
  float acc = 0.f;
#pragma unroll
  for (int s = 0; s < 64; s += 4) {
    float4 a = *reinterpret_cast<const float4*>(&p0[s]);
    float4 c = *reinterpret_cast<const float4*>(&p1[s]);
    acc += a.x*a.x + a.y*a.y + a.z*a.z + a.w*a.w
         + c.x*c.x + c.y*c.y + c.z*c.z + c.w*c.w;
  }
  ws[OFF_XRMS + row*TC + j] = sqrtf(acc * (0.5f/64.f) + 1e-7f);
}

// ---------------------------------------------------------------- decaying-max scan
__global__ __launch_bounds__(256) void k_scan(const float* __restrict__ rel_alphas,
                                              float* __restrict__ ws)
{
  __shared__ float sA[TC], sB[TC];
  int row = blockIdx.x;
  int tid = threadIdx.x;
  float kdec = 1.f - rel_alphas[row >> 3];   // reference's repeat() indexing
  const float* xr = ws + OFF_XRMS + row*TC;
  for (int i = tid; i < TC; i += 256) sA[i] = xr[i];
  __syncthreads();
  float* in = sA; float* outp = sB;
  for (int off = 1; off < 2048; off <<= 1) {
    float kp = powf(kdec, (float)off);
    for (int i = tid; i < TC; i += 256) {
      float v = in[i];
      if (i >= off) v = fmaxf(v, in[i-off] * kp);
      outp[i] = v;
    }
    __syncthreads();
    float* tmp = in; in = outp; outp = tmp;
  }
  float* env = ws + OFF_ENV + row*TC;
  for (int i = tid; i < TC; i += 256) env[i] = in[i];
}

// ---------------------------------------------------------------- gain + combine
__global__ __launch_bounds__(256) void k_gain(const float* __restrict__ params,
                                              const float* __restrict__ kneep,
                                              float* __restrict__ ws)
{
  int b = blockIdx.x;
  int t = blockIdx.y * 256 + threadIdx.x;
  if (t >= NT) return;
  const float* bands = ws + OFF_BANDS;
  const float* env = ws + OFF_ENV;
  float knee = kneep[0];
  float halfk = 0.5f * knee;
  float inv2k = 1.f / (2.f * knee);
  const float scale = (float)(1377.0 / 88199.0);
  float pos = (float)t * scale;
  int i0 = (int)floorf(pos);
  i0 = i0 < 0 ? 0 : (i0 > TC - 2 ? TC - 2 : i0);
  float frac = pos - (float)i0;
  const int tacol[3] = {3, 2, 1};
  const int tbcol[3] = {6, 5, 4};
  const float asl[3] = {1.f, (float)(1.0 - 1.0/66.7), (float)(1.0 - 1.0/66.7)};
  const float bsl = (float)(1.0 - 1.0/4.17);
  const float og[3] = {10.3f, 5.7f, 10.3f};
  float c0 = 0.f, c1 = 0.f;
#pragma unroll
  for (int band = 0; band < 3; ++band) {
    int row = b*3 + band;
    float e = env[row*TC + i0] * (1.f - frac) + env[row*TC + i0 + 1] * frac;
    float edb = 20.f * log10f(e + 1e-7f);
    float ta = params[b*7 + tacol[band]];
    float tb = params[b*7 + tbcol[band]];
    float d1 = edb - ta;
    float gk1 = asl[band] * (d1 + halfk) * (d1 + halfk) * inv2k;
    float ka = (fabsf(d1) <= halfk) ? gk1 : (d1 > halfk ? asl[band]*d1 : 0.f);
    float d2 = tb - edb;
    float gk2 = bsl * (d2 + halfk) * (d2 + halfk) * inv2k;
    float kb = (fabsf(d2) <= halfk) ? gk2 : (d2 > halfk ? bsl*d2 : 0.f);
    float gdb = -ka + kb + og[band];
    gdb = fminf(fmaxf(gdb, -80.f), 40.f);
    float g = exp2f(gdb * 0.16609640474436812f);   // 10^(gdb/20)
    c0 += bands[(row*2 + 0)*NT + t] * g;
    c1 += bands[(row*2 + 1)*NT + t] * g;
  }
  float* comb = ws + OFF_COMB;
  comb[(b*2 + 0)*NT + t] = c0;
  comb[(b*2 + 1)*NT + t] = c1;
}

// ---------------------------------------------------------------- MFMA conv net
// LDS activations bf16, TRANSPOSED: actT[pos][ic], pitch 72 shorts (bank-safe).
// Per layer: out[oc][p] = sum_kk A[oc][kk] * B[kk][p], kk = k*64+ic, K=192.
// A pre-packed per-lane (k_prep). B-frag = one ds_read_b128 (8 consecutive ic).
#define PITCH 72

__device__ __forceinline__ void mfma_layer(const short* in, short* outb,
    const short* __restrict__ apk, const float* __restrict__ bias,
    const int d, int t0, int wave, int lane)
{
  int quad = lane >> 4, l16 = lane & 15;
  short8v a[6];
#pragma unroll
  for (int s = 0; s < 6; ++s)
    a[s] = *(const short8v*)&apk[(((wave*6 + s)*64) + lane)*8];
  float4 bv = *(const float4*)&bias[wave*16 + quad*4];
  float4v acc[6];
#pragma unroll
  for (int n = 0; n < 6; ++n) { acc[n][0]=bv.x; acc[n][1]=bv.y; acc[n][2]=bv.z; acc[n][3]=bv.w; }
#pragma unroll
  for (int s = 0; s < 6; ++s) {
    int k = s >> 1;
    int ic0 = (s & 1)*32 + quad*8;
#pragma unroll
    for (int n = 0; n < 6; ++n) {
      int row = n*16 + l16 + (k - 1)*d;
      row = row < 0 ? 0 : (row > 95 ? 95 : row);   // clamped reads land in dead halo only
      short8v bf = *(const short8v*)&in[row*PITCH + ic0];
      acc[n] = __builtin_amdgcn_mfma_f32_16x16x32_bf16(a[s], bf, acc[n], 0, 0, 0);
    }
  }
  int ocb = wave*16 + quad*4;
#pragma unroll
  for (int n = 0; n < 6; ++n) {
    int p = n*16 + l16;
    int t = t0 - 16 + p;
    bool z = (t < 0) | (t >= NT);
    short4v r;
#pragma unroll
    for (int rg = 0; rg < 4; ++rg) {
      float v = z ? 0.f : geluf(acc[n][rg]);
      r[rg] = f2bf(v);
    }
    *(short4v*)&outb[p*PITCH + ocb] = r;
  }
}

__global__ __launch_bounds__(256) void k_convnet(
    const float* __restrict__ audio, const float* __restrict__ params,
    const float* __restrict__ b0, const float* __restrict__ b1,
    const float* __restrict__ b2, const float* __restrict__ b3,
    const float* __restrict__ b4, const float* __restrict__ ws,
    float* __restrict__ out)
{
  __shared__ float cmb[2][96];
  __shared__ __align__(16) short actA[96*PITCH];
  __shared__ __align__(16) short actB[96*PITCH];
  int tile = blockIdx.x, b = blockIdx.y;
  int t0 = tile * 64;
  int tid = threadIdx.x;
  int wave = tid >> 6, lane = tid & 63;
  const float* comb = ws + OFF_COMB;
  for (int i = tid; i < 192; i += 256) {
    int ic = i / 96, p = i - ic * 96;
    int t = t0 - 16 + p;
    cmb[ic][p] = (t >= 0 && t < NT) ? comb[(b*2 + ic)*NT + t] : 0.f;
  }
  __syncthreads();

  // ---- L0 (VALU): cin=2, d=1 -> actA (bf16 transposed)
  {
    const float* w = ws + OFF_WT0;
    int ow = wave * 16;
    float acc[2][16];
#pragma unroll
    for (int o = 0; o < 16; ++o) { float bb = b0[ow + o]; acc[0][o] = bb; acc[1][o] = bb; }
    int q[2];
#pragma unroll
    for (int c = 0; c < 2; ++c) {
      int p = c*64 + lane;
      q[c] = p < 1 ? 1 : (p > 94 ? 94 : p);
    }
#pragma unroll
    for (int k = 0; k < 3; ++k)
#pragma unroll
      for (int ic = 0; ic < 2; ++ic) {
        float x0 = cmb[ic][q[0] - 1 + k];
        float x1 = cmb[ic][q[1] - 1 + k];
#pragma unroll
        for (int ob = 0; ob < 4; ++ob) {
          float4 wv = *(const float4*)&w[(k*2 + ic)*64 + ow + ob*4];
          acc[0][ob*4+0] += wv.x*x0; acc[0][ob*4+1] += wv.y*x0; acc[0][ob*4+2] += wv.z*x0; acc[0][ob*4+3] += wv.w*x0;
          acc[1][ob*4+0] += wv.x*x1; acc[1][ob*4+1] += wv.y*x1; acc[1][ob*4+2] += wv.z*x1; acc[1][ob*4+3] += wv.w*x1;
        }
      }
#pragma unroll
    for (int c = 0; c < 2; ++c) {
      int p = c*64 + lane;
      if (p < 96) {
        int t = t0 - 16 + p;
        bool z = (t < 0) | (t >= NT);
        short8v r0, r1;
#pragma unroll
        for (int o = 0; o < 8; ++o) {
          r0[o] = f2bf(z ? 0.f : geluf(acc[c][o]));
          r1[o] = f2bf(z ? 0.f : geluf(acc[c][o + 8]));
        }
        *(short8v*)&actA[p*PITCH + ow] = r0;
        *(short8v*)&actA[p*PITCH + ow + 8] = r1;
      }
    }
  }
  __syncthreads();

  const short* apk = (const short*)(ws + OFF_ABF);
  mfma_layer(actA, actB, apk,           b1, 2, t0, wave, lane);
  __syncthreads();
  mfma_layer(actB, actA, apk + 12288,   b2, 4, t0, wave, lane);
  __syncthreads();
  mfma_layer(actA, actB, apk + 24576,   b3, 8, t0, wave, lane);
  __syncthreads();

  // ---- L4 (VALU): cout=2, d=1, reads actB; + final mix
  if (tid < 128) {
    int ch = tid >> 6, px = tid & 63, p = 16 + px;
    const float* w4f = ws + OFF_W4F + ch*192;
    float acc = b4[ch];
#pragma unroll
    for (int k = 0; k < 3; ++k) {
      int row = p + k - 1;
#pragma unroll
      for (int icb = 0; icb < 8; ++icb) {
        short8v xv = *(const short8v*)&actB[row*PITCH + icb*8];
        float4 wA = *(const float4*)&w4f[k*64 + icb*8];
        float4 wB = *(const float4*)&w4f[k*64 + icb*8 + 4];
        acc += wA.x*bf2f(xv[0]) + wA.y*bf2f(xv[1]) + wA.z*bf2f(xv[2]) + wA.w*bf2f(xv[3])
             + wB.x*bf2f(xv[4]) + wB.y*bf2f(xv[5]) + wB.z*bf2f(xv[6]) + wB.w*bf2f(xv[7]);
      }
    }
    int t = t0 + px;
    if (t < NT) {
      float amt = params[b*7];
      float aud = audio[(b*2 + ch)*NT + t];
      out[(b*2 + ch)*NT + t] = (1.f - amt)*aud + amt*(cmb[ch][16 + px] + acc);
    }
  }
}

// ----------------------------------------------------------------
extern "C" void kernel_launch(void* const* d_in, const int* in_sizes, int n_in,
                              void* d_out, int out_size, void* d_ws, size_t ws_size,
                              hipStream_t stream)
{
  (void)in_sizes; (void)n_in; (void)out_size; (void)ws_size;
  const float* audio = (const float*)d_in[0];
  const float* params = (const float*)d_in[1];
  const float* rel   = (const float*)d_in[2];
  const float* knee  = (const float*)d_in[3];
  const float* irLL  = (const float*)d_in[4];
  const float* irLH  = (const float*)d_in[5];
  const float* irHL  = (const float*)d_in[6];
  const float* irHH  = (const float*)d_in[7];
  const float* w0 = (const float*)d_in[8];  const float* b0 = (const float*)d_in[9];
  const float* w1 = (const float*)d_in[10]; const float* b1 = (const float*)d_in[11];
  const float* w2 = (const float*)d_in[12]; const float* b2 = (const float*)d_in[13];
  const float* w3 = (const float*)d_in[14]; const float* b3 = (const float*)d_in[15];
  const float* w4 = (const float*)d_in[16]; const float* b4 = (const float*)d_in[17];
  float* out = (float*)d_out;
  float* ws  = (float*)d_ws;

  hipLaunchKernelGGL(k_prep, dim3(48, 6), dim3(256), 0, stream,
                     irLL, irLH, irHL, irHH, w0, w1, w2, w3, w4, ws);
  hipLaunchKernelGGL(k_fir, dim3(16, 87), dim3(256), 0, stream, audio, ws);
  hipLaunchKernelGGL(k_rms, dim3(24, 22), dim3(64), 0, stream, ws);
  hipLaunchKernelGGL(k_scan, dim3(24), dim3(256), 0, stream, rel, ws);
  hipLaunchKernelGGL(k_gain, dim3(8, 345), dim3(256), 0, stream, params, knee, ws);
  hipLaunchKernelGGL(k_convnet, dim3(1379, 8), dim3(256), 0, stream,
                     audio, params, b0, b1, b2, b3, b4, ws, out);
}

// Round 3
// 467.680 us; speedup vs baseline: 4.0198x; 1.3085x over previous
//
#include <hip/hip_runtime.h>
#include <math.h>

#define NT 88200        // T
#define NB 8            // batch
#define TC 1378         // T // 64

static constexpr float IN_GAIN_F = 1.8197008586099834f; // 10^(5.2/20)

// ---- workspace layout (float offsets) ----
#define OFF_W     0            // composite flipped FIR weights, 3 x 1024
#define OFF_WT0   3072         // L0 weights [k][ic][oc] fp32 (384)
#define OFF_W4F   3456         // L4 weights [ch][k][ic] fp32 (384)
#define OFF_ABF   3840         // MFMA A-frag bf16 packs, 3 layers x 12288 shorts
#define OFF_BANDS 22272        // [B][3][C][T] = 4233600
#define OFF_XRMS  4255872      // [24][TC]
#define OFF_ENV   4288944      // [24][TC]
#define OFF_COMB  4322016      // [B][C][T] = 1411200

typedef __attribute__((ext_vector_type(8))) short short8v;
typedef __attribute__((ext_vector_type(4))) short short4v;
typedef __attribute__((ext_vector_type(4))) float float4v;

// Branchless erf: Abramowitz-Stegun 7.1.26, |err| <= 1.5e-7 (exact at bf16).
__device__ __forceinline__ float erf_fast(float u) {
  float au = fabsf(u);
  float t = __builtin_amdgcn_rcpf(fmaf(0.3275911f, au, 1.f));
  float p = fmaf(fmaf(fmaf(fmaf(1.061405429f, t, -1.453152027f), t,
                  1.421413741f), t, -0.284496736f), t, 0.254829592f) * t;
  float ex = __builtin_amdgcn_exp2f(au * au * -1.44269504f);
  float r = fmaf(-p, ex, 1.f);
  return copysignf(r, u);
}
__device__ __forceinline__ float geluf(float x) {
  return 0.5f * x * (1.f + erf_fast(x * 0.7071067811865476f));
}
__device__ __forceinline__ short f2bf(float x) {
  unsigned int u = __float_as_uint(x);
  u += 0x7fffu + ((u >> 16) & 1u);        // RNE
  return (short)(u >> 16);
}
__device__ __forceinline__ float bf2f(short s) {
  return __uint_as_float(((unsigned int)(unsigned short)s) << 16);
}

// ---------------------------------------------------------------- prep
__global__ __launch_bounds__(256) void k_prep(
    const float* __restrict__ irLL, const float* __restrict__ irLH,
    const float* __restrict__ irHL, const float* __restrict__ irHH,
    const float* __restrict__ w0, const float* __restrict__ w1,
    const float* __restrict__ w2, const float* __restrict__ w3,
    const float* __restrict__ w4, float* __restrict__ ws)
{
  int gid = blockIdx.x * 256 + threadIdx.x;
  int task = blockIdx.y;
  if (task == 0) {
    if (gid >= 3072) return;
    int band = gid >> 10, j = gid & 1023;
    float v = 0.f;
    if (j < 1023) {
      if (band == 2) {                      // low: 512-tap, right-aligned
        v = (j >= 511) ? irLL[j - 511] : 0.f;
      } else {                              // high/mid: conv(irLH, irH?)
        const float* wb = (band == 0) ? irHH : irHL;
        int lo = j - 511; if (lo < 0) lo = 0;
        int hi = (j < 511) ? j : 511;
        float acc = 0.f;
        for (int i = lo; i <= hi; ++i) acc += irLH[i] * wb[j - i];
        v = acc;
      }
    }
    ws[OFF_W + gid] = v;
  } else if (task == 1) {                   // wT0[k][ic][oc], cin=2
    if (gid >= 384) return;
    int k = gid / 128, rem = gid - k * 128;
    int ic = rem >> 6, oc = rem & 63;
    ws[OFF_WT0 + gid] = w0[(oc * 2 + ic) * 3 + k];
  } else if (task == 2) {                   // w4f[ch][k][ic]
    if (gid >= 384) return;
    int ch = gid / 192, rem = gid - ch * 192;
    int k = rem >> 6, ic = rem & 63;
    ws[OFF_W4F + gid] = w4[(ch * 64 + ic) * 3 + k];
  } else {                                  // A-pack layer l (w1..w3)
    int l = task - 3;
    if (gid >= 12288) return;
    const float* wl = (l == 0) ? w1 : (l == 1) ? w2 : w3;
    int wm = gid / 3072;
    int rem = gid - wm * 3072;
    int s = rem / 512;
    int rem2 = rem - s * 512;
    int lane = rem2 >> 3;
    int j = gid & 7;
    int m = wm * 16 + (lane & 15);               // oc
    int kk = s * 32 + ((lane >> 4) << 3) + j;    // flattened K = k*64+ic
    int k = kk >> 6, ic = kk & 63;
    short* ap = (short*)(ws + OFF_ABF);
    ap[l * 12288 + gid] = f2bf(wl[(m * 64 + ic) * 3 + k]);
  }
}

// ---------------------------------------------------------------- band FIR
__global__ __launch_bounds__(256) void k_fir(const float* __restrict__ audio,
                                             float* __restrict__ ws)
{
  __shared__ float xs[2048];
  __shared__ float wl[3][1024];
  int bc = blockIdx.x;               // b*2 + c
  int t0 = blockIdx.y * 1024;
  int tid = threadIdx.x;
  const float* Wc = ws + OFF_W;
  for (int i = tid; i < 3072; i += 256) wl[i >> 10][i & 1023] = Wc[i];
  const float* x = audio + bc * NT;
  for (int i = tid; i < 2048; i += 256) {
    int g = t0 - 1022 + i;
    xs[i] = (g >= 0 && g < NT) ? x[g] * IN_GAIN_F : 0.f;
  }
  __syncthreads();

  int base = tid * 4;
  float a0[4] = {0,0,0,0}, a1[4] = {0,0,0,0}, a2[4] = {0,0,0,0};
  float4 xv0 = *reinterpret_cast<const float4*>(&xs[base]);
  int j = 0;
  for (; j < 508; j += 4) {          // low band has zero taps here
    float4 xv1 = *reinterpret_cast<const float4*>(&xs[base + j + 4]);
    float xw[8] = {xv0.x, xv0.y, xv0.z, xv0.w, xv1.x, xv1.y, xv1.z, xv1.w};
    float4 w0v = *reinterpret_cast<const float4*>(&wl[0][j]);
    float4 w1v = *reinterpret_cast<const float4*>(&wl[1][j]);
#pragma unroll
    for (int r = 0; r < 4; ++r) {
      a0[r] += w0v.x*xw[r] + w0v.y*xw[r+1] + w0v.z*xw[r+2] + w0v.w*xw[r+3];
      a1[r] += w1v.x*xw[r] + w1v.y*xw[r+1] + w1v.z*xw[r+2] + w1v.w*xw[r+3];
    }
    xv0 = xv1;
  }
  for (; j < 1024; j += 4) {
    float4 xv1 = *reinterpret_cast<const float4*>(&xs[base + j + 4]);
    float xw[8] = {xv0.x, xv0.y, xv0.z, xv0.w, xv1.x, xv1.y, xv1.z, xv1.w};
    float4 w0v = *reinterpret_cast<const float4*>(&wl[0][j]);
    float4 w1v = *reinterpret_cast<const float4*>(&wl[1][j]);
    float4 w2v = *reinterpret_cast<const float4*>(&wl[2][j]);
#pragma unroll
    for (int r = 0; r < 4; ++r) {
      a0[r] += w0v.x*xw[r] + w0v.y*xw[r+1] + w0v.z*xw[r+2] + w0v.w*xw[r+3];
      a1[r] += w1v.x*xw[r] + w1v.y*xw[r+1] + w1v.z*xw[r+2] + w1v.w*xw[r+3];
      a2[r] += w2v.x*xw[r] + w2v.y*xw[r+1] + w2v.z*xw[r+2] + w2v.w*xw[r+3];
    }
    xv0 = xv1;
  }
  int b = bc >> 1, c = bc & 1;
  int t = t0 + base;
  if (t < NT) {
    float* bands = ws + OFF_BANDS;
    *reinterpret_cast<float4*>(&bands[((b*3+0)*2 + c)*NT + t]) = make_float4(a0[0],a0[1],a0[2],a0[3]);
    *reinterpret_cast<float4*>(&bands[((b*3+1)*2 + c)*NT + t]) = make_float4(a1[0],a1[1],a1[2],a1[3]);
    *reinterpret_cast<float4*>(&bands[((b*3+2)*2 + c)*NT + t]) = make_float4(a2[0],a2[1],a2[2],a2[3]);
  }
}

// ---------------------------------------------------------------- block RMS
__global__ __launch_bounds__(64) void k_rms(float* __restrict__ ws)
{
  int row = blockIdx.x;                      // b*3 + band
  int j = blockIdx.y * 64 + threadIdx.x;
  if (j >= TC) return;
  const float* bnd = ws + OFF_BANDS;
  const float* p0 = bnd + (row*2 + 0)*NT + j*64;
  const float* p1 = bnd + (row*2 + 1)*NT + j*64;
  float acc = 0.f;
#pragma unroll
  for (int s = 0; s < 64; s += 4) {
    float4 a = *reinterpret_cast<const float4*>(&p0[s]);
    float4 c = *reinterpret_cast<const float4*>(&p1[s]);
    acc += a.x*a.x + a.y*a.y + a.z*a.z + a.w*a.w
         + c.x*c.x + c.y*c.y + c.z*c.z + c.w*c.w;
  }
  ws[OFF_XRMS + row*TC + j] = sqrtf(acc * (0.5f/64.f) + 1e-7f);
}

// ---------------------------------------------------------------- decaying-max scan
__global__ __launch_bounds__(256) void k_scan(const float* __restrict__ rel_alphas,
                                              float* __restrict__ ws)
{
  __shared__ float sA[TC], sB[TC];
  int row = blockIdx.x;
  int tid = threadIdx.x;
  float kdec = 1.f - rel_alphas[row >> 3];   // reference's repeat() indexing
  const float* xr = ws + OFF_XRMS + row*TC;
  for (int i = tid; i < TC; i += 256) sA[i] = xr[i];
  __syncthreads();
  float* in = sA; float* outp = sB;
  for (int off = 1; off < 2048; off <<= 1) {
    float kp = powf(kdec, (float)off);
    for (int i = tid; i < TC; i += 256) {
      float v = in[i];
      if (i >= off) v = fmaxf(v, in[i-off] * kp);
      outp[i] = v;
    }
    __syncthreads();
    float* tmp = in; in = outp; outp = tmp;
  }
  float* env = ws + OFF_ENV + row*TC;
  for (int i = tid; i < TC; i += 256) env[i] = in[i];
}

// ---------------------------------------------------------------- gain + combine
__global__ __launch_bounds__(256) void k_gain(const float* __restrict__ params,
                                              const float* __restrict__ kneep,
                                              float* __restrict__ ws)
{
  int b = blockIdx.x;
  int t = blockIdx.y * 256 + threadIdx.x;
  if (t >= NT) return;
  const float* bands = ws + OFF_BANDS;
  const float* env = ws + OFF_ENV;
  float knee = kneep[0];
  float halfk = 0.5f * knee;
  float inv2k = 1.f / (2.f * knee);
  const float scale = (float)(1377.0 / 88199.0);
  float pos = (float)t * scale;
  int i0 = (int)floorf(pos);
  i0 = i0 < 0 ? 0 : (i0 > TC - 2 ? TC - 2 : i0);
  float frac = pos - (float)i0;
  const int tacol[3] = {3, 2, 1};
  const int tbcol[3] = {6, 5, 4};
  const float asl[3] = {1.f, (float)(1.0 - 1.0/66.7), (float)(1.0 - 1.0/66.7)};
  const float bsl = (float)(1.0 - 1.0/4.17);
  const float og[3] = {10.3f, 5.7f, 10.3f};
  float c0 = 0.f, c1 = 0.f;
#pragma unroll
  for (int band = 0; band < 3; ++band) {
    int row = b*3 + band;
    float e = env[row*TC + i0] * (1.f - frac) + env[row*TC + i0 + 1] * frac;
    float edb = 20.f * log10f(e + 1e-7f);
    float ta = params[b*7 + tacol[band]];
    float tb = params[b*7 + tbcol[band]];
    float d1 = edb - ta;
    float gk1 = asl[band] * (d1 + halfk) * (d1 + halfk) * inv2k;
    float ka = (fabsf(d1) <= halfk) ? gk1 : (d1 > halfk ? asl[band]*d1 : 0.f);
    float d2 = tb - edb;
    float gk2 = bsl * (d2 + halfk) * (d2 + halfk) * inv2k;
    float kb = (fabsf(d2) <= halfk) ? gk2 : (d2 > halfk ? bsl*d2 : 0.f);
    float gdb = -ka + kb + og[band];
    gdb = fminf(fmaxf(gdb, -80.f), 40.f);
    float g = exp2f(gdb * 0.16609640474436812f);   // 10^(gdb/20)
    c0 += bands[(row*2 + 0)*NT + t] * g;
    c1 += bands[(row*2 + 1)*NT + t] * g;
  }
  float* comb = ws + OFF_COMB;
  comb[(b*2 + 0)*NT + t] = c0;
  comb[(b*2 + 1)*NT + t] = c1;
}

// ---------------------------------------------------------------- MFMA conv net
// 128 outputs/block, span 160 (halo 16/side). 8 waves: wq=wave&3 -> oc group
// of 16, half=wave>>2 -> 5 N-tiles. Activations bf16 transposed [pos][ic],
// pitch 72 shorts. Halo corruption from edge clamps consumes 1+2+4+8+1=16,
// never reaching live outputs p in [16,144).
#define PITCH 72
#define SPAN 160
#define TILE 128

__device__ __forceinline__ void mfma_layer(const short* in, short* outb,
    const short* __restrict__ apk, const float* __restrict__ bias,
    const int d, int t0, int wq, int half, int lane)
{
  int quad = lane >> 4, l16 = lane & 15;
  short8v a[6];
#pragma unroll
  for (int s = 0; s < 6; ++s)
    a[s] = *(const short8v*)&apk[(((wq*6 + s)*64) + lane)*8];
  float4 bv = *(const float4*)&bias[wq*16 + quad*4];
  float4v acc[5];
#pragma unroll
  for (int n = 0; n < 5; ++n) { acc[n][0]=bv.x; acc[n][1]=bv.y; acc[n][2]=bv.z; acc[n][3]=bv.w; }
#pragma unroll
  for (int s = 0; s < 6; ++s) {
    int k = s >> 1;
    int ic0 = (s & 1)*32 + quad*8;
#pragma unroll
    for (int n = 0; n < 5; ++n) {
      int row = (half*5 + n)*16 + l16 + (k - 1)*d;
      row = row < 0 ? 0 : (row > SPAN-1 ? SPAN-1 : row);
      short8v bf = *(const short8v*)&in[row*PITCH + ic0];
      acc[n] = __builtin_amdgcn_mfma_f32_16x16x32_bf16(a[s], bf, acc[n], 0, 0, 0);
    }
  }
  int ocb = wq*16 + quad*4;
#pragma unroll
  for (int n = 0; n < 5; ++n) {
    int p = (half*5 + n)*16 + l16;
    int t = t0 - 16 + p;
    bool z = (t < 0) | (t >= NT);
    short4v r;
#pragma unroll
    for (int rg = 0; rg < 4; ++rg) {
      float v = z ? 0.f : geluf(acc[n][rg]);
      r[rg] = f2bf(v);
    }
    *(short4v*)&outb[p*PITCH + ocb] = r;
  }
}

__global__ __launch_bounds__(512) void k_convnet(
    const float* __restrict__ audio, const float* __restrict__ params,
    const float* __restrict__ b0, const float* __restrict__ b1,
    const float* __restrict__ b2, const float* __restrict__ b3,
    const float* __restrict__ b4, const float* __restrict__ ws,
    float* __restrict__ out)
{
  __shared__ float cmb[2][SPAN];
  __shared__ __align__(16) short actA[SPAN*PITCH];
  __shared__ __align__(16) short actB[SPAN*PITCH];
  int tile = blockIdx.x, b = blockIdx.y;
  int t0 = tile * TILE;
  int tid = threadIdx.x;
  int wave = tid >> 6, lane = tid & 63;
  const float* comb = ws + OFF_COMB;
  for (int i = tid; i < 2*SPAN; i += 512) {
    int ic = i / SPAN, p = i - ic * SPAN;
    int t = t0 - 16 + p;
    cmb[ic][p] = (t >= 0 && t < NT) ? comb[(b*2 + ic)*NT + t] : 0.f;
  }
  __syncthreads();

  // ---- L0 (VALU): cin=2, d=1 -> actA. wave -> 8 ocs, lanes x3 chunks cover 160 pos
  {
    const float* w = ws + OFF_WT0;
    int ow = wave * 8;
    float acc[3][8];
#pragma unroll
    for (int o = 0; o < 8; ++o) {
      float bb = b0[ow + o];
      acc[0][o] = bb; acc[1][o] = bb; acc[2][o] = bb;
    }
    int q[3];
#pragma unroll
    for (int c = 0; c < 3; ++c) {
      int p = c*64 + lane;
      q[c] = p < 1 ? 1 : (p > SPAN-2 ? SPAN-2 : p);
    }
#pragma unroll
    for (int k = 0; k < 3; ++k)
#pragma unroll
      for (int ic = 0; ic < 2; ++ic) {
        float x0 = cmb[ic][q[0] - 1 + k];
        float x1 = cmb[ic][q[1] - 1 + k];
        float x2 = cmb[ic][q[2] - 1 + k];
        float4 wa = *(const float4*)&w[(k*2 + ic)*64 + ow];
        float4 wb = *(const float4*)&w[(k*2 + ic)*64 + ow + 4];
        acc[0][0] += wa.x*x0; acc[0][1] += wa.y*x0; acc[0][2] += wa.z*x0; acc[0][3] += wa.w*x0;
        acc[0][4] += wb.x*x0; acc[0][5] += wb.y*x0; acc[0][6] += wb.z*x0; acc[0][7] += wb.w*x0;
        acc[1][0] += wa.x*x1; acc[1][1] += wa.y*x1; acc[1][2] += wa.z*x1; acc[1][3] += wa.w*x1;
        acc[1][4] += wb.x*x1; acc[1][5] += wb.y*x1; acc[1][6] += wb.z*x1; acc[1][7] += wb.w*x1;
        acc[2][0] += wa.x*x2; acc[2][1] += wa.y*x2; acc[2][2] += wa.z*x2; acc[2][3] += wa.w*x2;
        acc[2][4] += wb.x*x2; acc[2][5] += wb.y*x2; acc[2][6] += wb.z*x2; acc[2][7] += wb.w*x2;
      }
#pragma unroll
    for (int c = 0; c < 3; ++c) {
      int p = c*64 + lane;
      if (p < SPAN) {
        int t = t0 - 16 + p;
        bool z = (t < 0) | (t >= NT);
        short8v r;
#pragma unroll
        for (int o = 0; o < 8; ++o)
          r[o] = f2bf(z ? 0.f : geluf(acc[c][o]));
        *(short8v*)&actA[p*PITCH + ow] = r;
      }
    }
  }
  __syncthreads();

  int wq = wave & 3, half = wave >> 2;
  const short* apk = (const short*)(ws + OFF_ABF);
  mfma_layer(actA, actB, apk,           b1, 2, t0, wq, half, lane);
  __syncthreads();
  mfma_layer(actB, actA, apk + 12288,   b2, 4, t0, wq, half, lane);
  __syncthreads();
  mfma_layer(actA, actB, apk + 24576,   b3, 8, t0, wq, half, lane);
  __syncthreads();

  // ---- L4 (VALU): cout=2, d=1, reads actB; + final mix
  if (tid < 256) {
    int ch = tid >> 7, px = tid & 127, p = 16 + px;
    const float* w4f = ws + OFF_W4F + ch*192;
    float acc = b4[ch];
#pragma unroll
    for (int k = 0; k < 3; ++k) {
      int row = p + k - 1;
#pragma unroll
      for (int icb = 0; icb < 8; ++icb) {
        short8v xv = *(const short8v*)&actB[row*PITCH + icb*8];
        float4 wA = *(const float4*)&w4f[k*64 + icb*8];
        float4 wB = *(const float4*)&w4f[k*64 + icb*8 + 4];
        acc += wA.x*bf2f(xv[0]) + wA.y*bf2f(xv[1]) + wA.z*bf2f(xv[2]) + wA.w*bf2f(xv[3])
             + wB.x*bf2f(xv[4]) + wB.y*bf2f(xv[5]) + wB.z*bf2f(xv[6]) + wB.w*bf2f(xv[7]);
      }
    }
    int t = t0 + px;
    if (t < NT) {
      float amt = params[b*7];
      float aud = audio[(b*2 + ch)*NT + t];
      out[(b*2 + ch)*NT + t] = (1.f - amt)*aud + amt*(cmb[ch][16 + px] + acc);
    }
  }
}

// ----------------------------------------------------------------
extern "C" void kernel_launch(void* const* d_in, const int* in_sizes, int n_in,
                              void* d_out, int out_size, void* d_ws, size_t ws_size,
                              hipStream_t stream)
{
  (void)in_sizes; (void)n_in; (void)out_size; (void)ws_size;
  const float* audio = (const float*)d_in[0];
  const float* params = (const float*)d_in[1];
  const float* rel   = (const float*)d_in[2];
  const float* knee  = (const float*)d_in[3];
  const float* irLL  = (const float*)d_in[4];
  const float* irLH  = (const float*)d_in[5];
  const float* irHL  = (const float*)d_in[6];
  const float* irHH  = (const float*)d_in[7];
  const float* w0 = (const float*)d_in[8];  const float* b0 = (const float*)d_in[9];
  const float* w1 = (const float*)d_in[10]; const float* b1 = (const float*)d_in[11];
  const float* w2 = (const float*)d_in[12]; const float* b2 = (const float*)d_in[13];
  const float* w3 = (const float*)d_in[14]; const float* b3 = (const float*)d_in[15];
  const float* w4 = (const float*)d_in[16]; const float* b4 = (const float*)d_in[17];
  float* out = (float*)d_out;
  float* ws  = (float*)d_ws;

  hipLaunchKernelGGL(k_prep, dim3(48, 6), dim3(256), 0, stream,
                     irLL, irLH, irHL, irHH, w0, w1, w2, w3, w4, ws);
  hipLaunchKernelGGL(k_fir, dim3(16, 87), dim3(256), 0, stream, audio, ws);
  hipLaunchKernelGGL(k_rms, dim3(24, 22), dim3(64), 0, stream, ws);
  hipLaunchKernelGGL(k_scan, dim3(24), dim3(256), 0, stream, rel, ws);
  hipLaunchKernelGGL(k_gain, dim3(8, 345), dim3(256), 0, stream, params, knee, ws);
  hipLaunchKernelGGL(k_convnet, dim3(690, 8), dim3(512), 0, stream,
                     audio, params, b0, b1, b2, b3, b4, ws, out);
}

// Round 5
// 340.895 us; speedup vs baseline: 5.5149x; 1.3719x over previous
//
#include <hip/hip_runtime.h>
#include <math.h>

#define NT 88200        // T
#define NB 8            // batch
#define TC 1378         // T // 64

static constexpr float IN_GAIN_F = 1.8197008586099834f; // 10^(5.2/20)

// ---- workspace layout (float offsets) ----
#define OFF_W     0            // composite flipped FIR weights, 3 x 1024 fp32
#define OFF_WT0   3072         // L0 weights [k][ic][oc] fp32 (384)
#define OFF_A4    3456         // L4 MFMA A-pack bf16 (3072 shorts = 1536 floats)
#define OFF_ABF   4992         // MFMA A-frag bf16 packs, 3 layers x 12288 shorts
#define OFF_BANDS 23424        // [B][3][C][T] = 4233600
#define OFF_XRMS  4257024      // [24][TC]
#define OFF_ENV   4290096      // [24][TC]
#define OFF_WHL   4290096      // bf16 hi/lo shifted tap tables (9216 shorts) — overlaps ENV:
                               //   written by k_prep2, read by k_firm, dead before k_scan writes ENV
#define OFF_COMB  4323168      // [B][C][T] = 1411200
// end 5734368 floats ~= 22.94 MB

typedef __attribute__((ext_vector_type(8))) short short8v;
typedef __attribute__((ext_vector_type(4))) short short4v;
typedef __attribute__((ext_vector_type(4))) float float4v;

// sigmoid-gelu: x*sigmoid(1.702x); |err| <= 0.021, reaches output only via res (~0.01 scale)
__device__ __forceinline__ float gelus(float x) {
  float e = __builtin_amdgcn_exp2f(-2.4554670f * x);
  return x * __builtin_amdgcn_rcpf(1.f + e);
}
__device__ __forceinline__ short f2bf(float x) {        // RNE (weights/prep)
  unsigned int u = __float_as_uint(x);
  u += 0x7fffu + ((u >> 16) & 1u);
  return (short)(u >> 16);
}
__device__ __forceinline__ short f2bft(float x) {       // truncate (activations)
  return (short)(__float_as_uint(x) >> 16);
}
__device__ __forceinline__ float bf2f(short s) {
  return __uint_as_float(((unsigned int)(unsigned short)s) << 16);
}

// ---------------------------------------------------------------- prep
// task 0: composite FIR taps (fp32); task 1: L0 reorder; task 2: L4 A-pack;
// tasks 3..5: MFMA A-packs for w1..w3.
__global__ __launch_bounds__(256) void k_prep(
    const float* __restrict__ irLL, const float* __restrict__ irLH,
    const float* __restrict__ irHL, const float* __restrict__ irHH,
    const float* __restrict__ w0, const float* __restrict__ w1,
    const float* __restrict__ w2, const float* __restrict__ w3,
    const float* __restrict__ w4, float* __restrict__ ws)
{
  int gid = blockIdx.x * 256 + threadIdx.x;
  int task = blockIdx.y;
  if (task == 0) {
    if (gid >= 3072) return;
    int band = gid >> 10, j = gid & 1023;
    float v = 0.f;
    if (j < 1023) {
      if (band == 2) {                      // low: 512-tap, right-aligned
        v = (j >= 511) ? irLL[j - 511] : 0.f;
      } else {                              // high/mid: conv(irLH, irH?)
        const float* wb = (band == 0) ? irHH : irHL;
        int lo = j - 511; if (lo < 0) lo = 0;
        int hi = (j < 511) ? j : 511;
        float acc = 0.f;
        for (int i = lo; i <= hi; ++i) acc += irLH[i] * wb[j - i];
        v = acc;
      }
    }
    ws[OFF_W + gid] = v;
  } else if (task == 1) {                   // wT0[k][ic][oc], cin=2
    if (gid >= 384) return;
    int k = gid / 128, rem = gid - k * 128;
    int ic = rem >> 6, oc = rem & 63;
    ws[OFF_WT0 + gid] = w0[(oc * 2 + ic) * 3 + k];
  } else if (task == 2) {                   // L4 A-pack: rows m=ch (2 live of 16)
    if (gid >= 3072) return;
    int s = gid >> 9;
    int lane = (gid - s * 512) >> 3;
    int j = gid & 7;
    int m = lane & 15, q = lane >> 4;
    int K = s * 32 + q * 8 + j;
    int k = K >> 6, ic = K & 63;
    float val = (m < 2) ? w4[(m * 64 + ic) * 3 + k] : 0.f;
    ((short*)(ws + OFF_A4))[gid] = f2bf(val);
  } else {                                  // A-pack layer l (w1..w3)
    int l = task - 3;
    if (gid >= 12288) return;
    const float* wl = (l == 0) ? w1 : (l == 1) ? w2 : w3;
    int wm = gid / 3072;
    int rem = gid - wm * 3072;
    int s = rem / 512;
    int rem2 = rem - s * 512;
    int lane = rem2 >> 3;
    int j = gid & 7;
    int m = wm * 16 + (lane & 15);               // oc
    int kk = s * 32 + ((lane >> 4) << 3) + j;    // flattened K = k*64+ic
    int k = kk >> 6, ic = kk & 63;
    short* ap = (short*)(ws + OFF_ABF);
    ap[l * 12288 + gid] = f2bf(wl[(m * 64 + ic) * 3 + k]);
  }
}

// prep2: bf16 hi/lo u-shifted tap tables (needs composite W from k_prep task 0).
// layout: table t (0=hi,1=lo) x band(4, band3=zeros) x 1152; entry j maps tap (j-64).
__global__ __launch_bounds__(256) void k_prep2(float* __restrict__ ws)
{
  int gid = blockIdx.x * 256 + threadIdx.x;   // 36*256 = 9216
  if (gid >= 9216) return;
  int t = gid / 4608;
  int idx = gid - t * 4608;
  int band = idx / 1152;
  int jj = idx - band * 1152 - 64;
  float v = (band < 3 && jj >= 0 && jj < 1024) ? ws[OFF_W + band * 1024 + jj] : 0.f;
  short h = f2bf(v);
  ((short*)(ws + OFF_WHL))[gid] = (t == 0) ? h : f2bf(v - bf2f(h));
}

// ---------------------------------------------------------------- MFMA band FIR
// y[band][T0+16u+n] = sum_j W[j] x[T0+16u+n+j-1022]; shift j'=j+16u folded into
// pre-shifted A tables (aligned: 16u*2B mult of 32). Rows m=band*5+u (15 live),
// cols n=16 time. B-frags from 4 parity copies of x so b64 reads are 8B-aligned.
// 3-chain split: wh*xh + wl*xh + wh*xl (FIR err ~2^-17).
#define FT 320
__global__ __launch_bounds__(256) void k_firm(const float* __restrict__ audio,
                                              float* __restrict__ ws)
{
  __shared__ short xh[4][1360];
  __shared__ short xl[4][1360];
  __shared__ __align__(16) short wt[9216];
  int bc = blockIdx.x, tile = blockIdx.y;
  int t0b = tile * FT;
  int tid = threadIdx.x;
  const uint4* wsrc = (const uint4*)((const short*)(ws + OFF_WHL));
  uint4* wdst = (uint4*)wt;
  for (int i = tid; i < 1152; i += 256) wdst[i] = wsrc[i];   // 9216 shorts = 1152 uint4 (r4 bug: was 576)
  const float* x = audio + bc * NT;
  for (int i = tid; i < 1360; i += 256) {
#pragma unroll
    for (int c = 0; c < 4; ++c) {
      int g = t0b - 1022 + i + c;
      float v = (g >= 0 && g < NT) ? x[g] * IN_GAIN_F : 0.f;
      short h = f2bf(v);
      xh[c][i] = h;
      xl[c][i] = f2bf(v - bf2f(h));
    }
  }
  __syncthreads();

  int wave = tid >> 6, lane = tid & 63;
  int q = lane >> 4, l16 = lane & 15;
  int band = (l16 >= 10) ? 2 : (l16 >= 5 ? 1 : 0);
  if (l16 == 15) band = 3;
  int u = l16 - band * 5;                       // band3 -> u=0 (zero taps)
  const short* pAh = wt + band * 1152 + 64 + q * 8 - u * 16;
  const short* pAl = pAh + 4608;
  int c = l16 & 3;
  int xoff = wave * 80 + q * 8 + ((l16 >> 2) << 2);
  const short* pBh = &xh[c][xoff];
  const short* pBl = &xl[c][xoff];
  float4v acc = {0.f, 0.f, 0.f, 0.f};
#pragma unroll 2
  for (int s = 0; s < 34; ++s) {
    short8v ah = *(const short8v*)(pAh + 32 * s);
    short8v al = *(const short8v*)(pAl + 32 * s);
    short4v bh0 = *(const short4v*)(pBh + 32 * s);
    short4v bh1 = *(const short4v*)(pBh + 32 * s + 4);
    short4v bl0 = *(const short4v*)(pBl + 32 * s);
    short4v bl1 = *(const short4v*)(pBl + 32 * s + 4);
    short8v bh = __builtin_shufflevector(bh0, bh1, 0, 1, 2, 3, 4, 5, 6, 7);
    short8v bl = __builtin_shufflevector(bl0, bl1, 0, 1, 2, 3, 4, 5, 6, 7);
    acc = __builtin_amdgcn_mfma_f32_16x16x32_bf16(ah, bh, acc, 0, 0, 0);
    acc = __builtin_amdgcn_mfma_f32_16x16x32_bf16(al, bh, acc, 0, 0, 0);
    acc = __builtin_amdgcn_mfma_f32_16x16x32_bf16(ah, bl, acc, 0, 0, 0);
  }
  int b = bc >> 1, ch = bc & 1;
  float* bands = ws + OFF_BANDS;
#pragma unroll
  for (int r = 0; r < 4; ++r) {
    int m = q * 4 + r;
    if (m < 15) {
      int bnd = (m >= 10) ? 2 : (m >= 5 ? 1 : 0);
      int uu = m - bnd * 5;
      int t = t0b + wave * 80 + uu * 16 + l16;
      if (t < NT) bands[((b * 3 + bnd) * 2 + ch) * NT + t] = acc[r];
    }
  }
}

// ---------------------------------------------------------------- block RMS
__global__ __launch_bounds__(64) void k_rms(float* __restrict__ ws)
{
  int row = blockIdx.x;
  int j = blockIdx.y * 64 + threadIdx.x;
  if (j >= TC) return;
  const float* bnd = ws + OFF_BANDS;
  const float* p0 = bnd + (row * 2 + 0) * NT + j * 64;
  const float* p1 = bnd + (row * 2 + 1) * NT + j * 64;
  float acc = 0.f;
#pragma unroll
  for (int s = 0; s < 64; s += 4) {
    float4 a = *reinterpret_cast<const float4*>(&p0[s]);
    float4 cc = *reinterpret_cast<const float4*>(&p1[s]);
    acc += a.x * a.x + a.y * a.y + a.z * a.z + a.w * a.w
         + cc.x * cc.x + cc.y * cc.y + cc.z * cc.z + cc.w * cc.w;
  }
  ws[OFF_XRMS + row * TC + j] = sqrtf(acc * (0.5f / 64.f) + 1e-7f);
}

// ---------------------------------------------------------------- decaying-max scan
__global__ __launch_bounds__(256) void k_scan(const float* __restrict__ rel_alphas,
                                              float* __restrict__ ws)
{
  __shared__ float sA[TC], sB[TC];
  int row = blockIdx.x;
  int tid = threadIdx.x;
  float kdec = 1.f - rel_alphas[row >> 3];   // reference's repeat() indexing
  float l2k = log2f(kdec);
  const float* xr = ws + OFF_XRMS + row * TC;
  for (int i = tid; i < TC; i += 256) sA[i] = xr[i];
  __syncthreads();
  float* in = sA; float* outp = sB;
  for (int off = 1; off < 2048; off <<= 1) {
    float kp = exp2f(l2k * (float)off);
    for (int i = tid; i < TC; i += 256) {
      float v = in[i];
      if (i >= off) v = fmaxf(v, in[i - off] * kp);
      outp[i] = v;
    }
    __syncthreads();
    float* tmp = in; in = outp; outp = tmp;
  }
  float* env = ws + OFF_ENV + row * TC;
  for (int i = tid; i < TC; i += 256) env[i] = in[i];
}

// ---------------------------------------------------------------- gain + combine
__global__ __launch_bounds__(256) void k_gain(const float* __restrict__ params,
                                              const float* __restrict__ kneep,
                                              float* __restrict__ ws)
{
  int b = blockIdx.x;
  int t = blockIdx.y * 256 + threadIdx.x;
  if (t >= NT) return;
  const float* bands = ws + OFF_BANDS;
  const float* env = ws + OFF_ENV;
  float knee = kneep[0];
  float halfk = 0.5f * knee;
  float inv2k = 1.f / (2.f * knee);
  const float scale = (float)(1377.0 / 88199.0);
  float pos = (float)t * scale;
  int i0 = (int)floorf(pos);
  i0 = i0 < 0 ? 0 : (i0 > TC - 2 ? TC - 2 : i0);
  float frac = pos - (float)i0;
  const int tacol[3] = {3, 2, 1};
  const int tbcol[3] = {6, 5, 4};
  const float asl[3] = {1.f, (float)(1.0 - 1.0 / 66.7), (float)(1.0 - 1.0 / 66.7)};
  const float bsl = (float)(1.0 - 1.0 / 4.17);
  const float og[3] = {10.3f, 5.7f, 10.3f};
  float c0 = 0.f, c1 = 0.f;
#pragma unroll
  for (int band = 0; band < 3; ++band) {
    int row = b * 3 + band;
    float e = env[row * TC + i0] * (1.f - frac) + env[row * TC + i0 + 1] * frac;
    float edb = 20.f * log10f(e + 1e-7f);
    float ta = params[b * 7 + tacol[band]];
    float tb = params[b * 7 + tbcol[band]];
    float d1 = edb - ta;
    float gk1 = asl[band] * (d1 + halfk) * (d1 + halfk) * inv2k;
    float ka = (fabsf(d1) <= halfk) ? gk1 : (d1 > halfk ? asl[band] * d1 : 0.f);
    float d2 = tb - edb;
    float gk2 = bsl * (d2 + halfk) * (d2 + halfk) * inv2k;
    float kb = (fabsf(d2) <= halfk) ? gk2 : (d2 > halfk ? bsl * d2 : 0.f);
    float gdb = -ka + kb + og[band];
    gdb = fminf(fmaxf(gdb, -80.f), 40.f);
    float g = exp2f(gdb * 0.16609640474436812f);   // 10^(gdb/20)
    c0 += bands[(row * 2 + 0) * NT + t] * g;
    c1 += bands[(row * 2 + 1) * NT + t] * g;
  }
  float* comb = ws + OFF_COMB;
  comb[(b * 2 + 0) * NT + t] = c0;
  comb[(b * 2 + 1) * NT + t] = c1;
}

// ---------------------------------------------------------------- MFMA conv net
#define PITCH 72
#define SPAN 160
#define TILE 128

__device__ __forceinline__ void mfma_layer(const short* in, short* outb,
    const short* __restrict__ apk, const float* __restrict__ bias,
    const int d, int t0, int wq, int half, int lane)
{
  int quad = lane >> 4, l16 = lane & 15;
  short8v a[6];
#pragma unroll
  for (int s = 0; s < 6; ++s)
    a[s] = *(const short8v*)&apk[(((wq * 6 + s) * 64) + lane) * 8];
  float4 bv = *(const float4*)&bias[wq * 16 + quad * 4];
  float4v acc[5];
#pragma unroll
  for (int n = 0; n < 5; ++n) { acc[n][0] = bv.x; acc[n][1] = bv.y; acc[n][2] = bv.z; acc[n][3] = bv.w; }
#pragma unroll
  for (int s = 0; s < 6; ++s) {
    int k = s >> 1;
    int ic0 = (s & 1) * 32 + quad * 8;
#pragma unroll
    for (int n = 0; n < 5; ++n) {
      int row = (half * 5 + n) * 16 + l16 + (k - 1) * d;
      row = row < 0 ? 0 : (row > SPAN - 1 ? SPAN - 1 : row);
      short8v bf = *(const short8v*)&in[row * PITCH + ic0];
      acc[n] = __builtin_amdgcn_mfma_f32_16x16x32_bf16(a[s], bf, acc[n], 0, 0, 0);
    }
  }
  int ocb = wq * 16 + quad * 4;
#pragma unroll
  for (int n = 0; n < 5; ++n) {
    int p = (half * 5 + n) * 16 + l16;
    int t = t0 - 16 + p;
    bool z = (t < 0) | (t >= NT);
    short4v r;
#pragma unroll
    for (int rg = 0; rg < 4; ++rg)
      r[rg] = f2bft(z ? 0.f : gelus(acc[n][rg]));
    *(short4v*)&outb[p * PITCH + ocb] = r;
  }
}

__global__ __launch_bounds__(512) void k_convnet(
    const float* __restrict__ audio, const float* __restrict__ params,
    const float* __restrict__ b0, const float* __restrict__ b1,
    const float* __restrict__ b2, const float* __restrict__ b3,
    const float* __restrict__ b4, const float* __restrict__ ws,
    float* __restrict__ out)
{
  __shared__ float cmb[2][SPAN];
  __shared__ __align__(16) short actA[SPAN * PITCH];
  __shared__ __align__(16) short actB[SPAN * PITCH];
  int tile = blockIdx.x, b = blockIdx.y;
  int t0 = tile * TILE;
  int tid = threadIdx.x;
  int wave = tid >> 6, lane = tid & 63;
  const float* comb = ws + OFF_COMB;
  for (int i = tid; i < 2 * SPAN; i += 512) {
    int ic = i / SPAN, p = i - ic * SPAN;
    int t = t0 - 16 + p;
    cmb[ic][p] = (t >= 0 && t < NT) ? comb[(b * 2 + ic) * NT + t] : 0.f;
  }
  __syncthreads();

  // ---- L0 (VALU): cin=2, d=1 -> actA
  {
    const float* w = ws + OFF_WT0;
    int ow = wave * 8;
    float acc[3][8];
#pragma unroll
    for (int o = 0; o < 8; ++o) {
      float bb = b0[ow + o];
      acc[0][o] = bb; acc[1][o] = bb; acc[2][o] = bb;
    }
    int q[3];
#pragma unroll
    for (int c = 0; c < 3; ++c) {
      int p = c * 64 + lane;
      q[c] = p < 1 ? 1 : (p > SPAN - 2 ? SPAN - 2 : p);
    }
#pragma unroll
    for (int k = 0; k < 3; ++k)
#pragma unroll
      for (int ic = 0; ic < 2; ++ic) {
        float x0 = cmb[ic][q[0] - 1 + k];
        float x1 = cmb[ic][q[1] - 1 + k];
        float x2 = cmb[ic][q[2] - 1 + k];
        float4 wa = *(const float4*)&w[(k * 2 + ic) * 64 + ow];
        float4 wb = *(const float4*)&w[(k * 2 + ic) * 64 + ow + 4];
        acc[0][0] += wa.x * x0; acc[0][1] += wa.y * x0; acc[0][2] += wa.z * x0; acc[0][3] += wa.w * x0;
        acc[0][4] += wb.x * x0; acc[0][5] += wb.y * x0; acc[0][6] += wb.z * x0; acc[0][7] += wb.w * x0;
        acc[1][0] += wa.x * x1; acc[1][1] += wa.y * x1; acc[1][2] += wa.z * x1; acc[1][3] += wa.w * x1;
        acc[1][4] += wb.x * x1; acc[1][5] += wb.y * x1; acc[1][6] += wb.z * x1; acc[1][7] += wb.w * x1;
        acc[2][0] += wa.x * x2; acc[2][1] += wa.y * x2; acc[2][2] += wa.z * x2; acc[2][3] += wa.w * x2;
        acc[2][4] += wb.x * x2; acc[2][5] += wb.y * x2; acc[2][6] += wb.z * x2; acc[2][7] += wb.w * x2;
      }
#pragma unroll
    for (int c = 0; c < 3; ++c) {
      int p = c * 64 + lane;
      if (p < SPAN) {
        int t = t0 - 16 + p;
        bool z = (t < 0) | (t >= NT);
        short8v r;
#pragma unroll
        for (int o = 0; o < 8; ++o)
          r[o] = f2bft(z ? 0.f : gelus(acc[c][o]));
        *(short8v*)&actA[p * PITCH + ow] = r;
      }
    }
  }
  __syncthreads();

  int wq = wave & 3, half = wave >> 2;
  const short* apk = (const short*)(ws + OFF_ABF);
  mfma_layer(actA, actB, apk,          b1, 2, t0, wq, half, lane);
  __syncthreads();
  mfma_layer(actB, actA, apk + 12288,  b2, 4, t0, wq, half, lane);
  __syncthreads();
  mfma_layer(actA, actB, apk + 24576,  b3, 8, t0, wq, half, lane);
  __syncthreads();

  // ---- L4 (MFMA): rows m=ch (2 live), cols = 16 positions per wave; + final mix
  {
    int q = lane >> 4, l16 = lane & 15;
    const short* ap4 = (const short*)(ws + OFF_A4);
    float4v acc = {0.f, 0.f, 0.f, 0.f};
    if (q == 0) { acc[0] = b4[0]; acc[1] = b4[1]; }
#pragma unroll
    for (int s = 0; s < 6; ++s) {
      short8v a4 = *(const short8v*)&ap4[(s * 64 + lane) * 8];
      int kt = s >> 1;
      int ic0 = (s & 1) * 32 + q * 8;
      int row = 16 + wave * 16 + l16 + kt - 1;
      short8v bf = *(const short8v*)&actB[row * PITCH + ic0];
      acc = __builtin_amdgcn_mfma_f32_16x16x32_bf16(a4, bf, acc, 0, 0, 0);
    }
    if (q == 0) {
      int t = t0 + wave * 16 + l16;
      if (t < NT) {
        float amt = params[b * 7];
#pragma unroll
        for (int r = 0; r < 2; ++r) {
          float aud = audio[(b * 2 + r) * NT + t];
          out[(b * 2 + r) * NT + t] =
              (1.f - amt) * aud + amt * (cmb[r][16 + wave * 16 + l16] + acc[r]);
        }
      }
    }
  }
}

// ----------------------------------------------------------------
extern "C" void kernel_launch(void* const* d_in, const int* in_sizes, int n_in,
                              void* d_out, int out_size, void* d_ws, size_t ws_size,
                              hipStream_t stream)
{
  (void)in_sizes; (void)n_in; (void)out_size; (void)ws_size;
  const float* audio = (const float*)d_in[0];
  const float* params = (const float*)d_in[1];
  const float* rel   = (const float*)d_in[2];
  const float* knee  = (const float*)d_in[3];
  const float* irLL  = (const float*)d_in[4];
  const float* irLH  = (const float*)d_in[5];
  const float* irHL  = (const float*)d_in[6];
  const float* irHH  = (const float*)d_in[7];
  const float* w0 = (const float*)d_in[8];  const float* b0 = (const float*)d_in[9];
  const float* w1 = (const float*)d_in[10]; const float* b1 = (const float*)d_in[11];
  const float* w2 = (const float*)d_in[12]; const float* b2 = (const float*)d_in[13];
  const float* w3 = (const float*)d_in[14]; const float* b3 = (const float*)d_in[15];
  const float* w4 = (const float*)d_in[16]; const float* b4 = (const float*)d_in[17];
  float* out = (float*)d_out;
  float* ws  = (float*)d_ws;

  hipLaunchKernelGGL(k_prep, dim3(48, 6), dim3(256), 0, stream,
                     irLL, irLH, irHL, irHH, w0, w1, w2, w3, w4, ws);
  hipLaunchKernelGGL(k_prep2, dim3(36), dim3(256), 0, stream, ws);
  hipLaunchKernelGGL(k_firm, dim3(16, 276), dim3(256), 0, stream, audio, ws);
  hipLaunchKernelGGL(k_rms, dim3(24, 22), dim3(64), 0, stream, ws);
  hipLaunchKernelGGL(k_scan, dim3(24), dim3(256), 0, stream, rel, ws);
  hipLaunchKernelGGL(k_gain, dim3(8, 345), dim3(256), 0, stream, params, knee, ws);
  hipLaunchKernelGGL(k_convnet, dim3(690, 8), dim3(512), 0, stream,
                     audio, params, b0, b1, b2, b3, b4, ws, out);
}

// Round 6
// 324.164 us; speedup vs baseline: 5.7995x; 1.0516x over previous
//
#include <hip/hip_runtime.h>
#include <math.h>

#define NT 88200        // T
#define NB 8            // batch
#define TC 1378         // T // 64

static constexpr float IN_GAIN_F = 1.8197008586099834f; // 10^(5.2/20)

// ---- workspace layout (float offsets) ----
#define OFF_A0    3072         // L0 MFMA A-pack bf16 (2048 shorts)
#define OFF_A4    4096         // L4 MFMA A-pack bf16 (3072 shorts)
#define OFF_ABF   5632         // MFMA A-frag bf16 packs, 3 layers x 12288 shorts
#define OFF_BANDS 24064        // [B][3][C][T] = 4233600
#define OFF_XRMS  4257664      // [24][TC]
#define OFF_ENV   4290736      // [24][TC]
#define OFF_WHL   4290736      // bf16 hi/lo shifted tap tables (9216 shorts) — overlaps ENV:
                               //   written by k_prep, read by k_firm, dead before k_scan writes ENV
// end 4323808 floats ~= 17.3 MB

typedef __attribute__((ext_vector_type(8))) short short8v;
typedef __attribute__((ext_vector_type(4))) short short4v;
typedef __attribute__((ext_vector_type(4))) float float4v;

// sigmoid-gelu: x*sigmoid(1.702x); |err| <= 0.021, reaches output only via res (~0.01 scale)
__device__ __forceinline__ float gelus(float x) {
  float e = __builtin_amdgcn_exp2f(-2.4554670f * x);
  return x * __builtin_amdgcn_rcpf(1.f + e);
}
__device__ __forceinline__ short f2bf(float x) {        // RNE
  unsigned int u = __float_as_uint(x);
  u += 0x7fffu + ((u >> 16) & 1u);
  return (short)(u >> 16);
}
__device__ __forceinline__ short f2bft(float x) {       // truncate
  return (short)(__float_as_uint(x) >> 16);
}
__device__ __forceinline__ float bf2f(short s) {
  return __uint_as_float(((unsigned int)(unsigned short)s) << 16);
}

// ---------------------------------------------------------------- prep
// task 0: composite FIR taps -> bf16 hi/lo shifted tables (WHL) incl. zero edges;
// task 1: L0 A-pack; task 2: L4 A-pack; tasks 3..5: A-packs for w1..w3.
__global__ __launch_bounds__(256) void k_prep(
    const float* __restrict__ irLL, const float* __restrict__ irLH,
    const float* __restrict__ irHL, const float* __restrict__ irHH,
    const float* __restrict__ w0, const float* __restrict__ w1,
    const float* __restrict__ w2, const float* __restrict__ w3,
    const float* __restrict__ w4, float* __restrict__ ws)
{
  int gid = blockIdx.x * 256 + threadIdx.x;
  int task = blockIdx.y;
  if (task == 0) {
    short* whl = (short*)(ws + OFF_WHL);
    if (gid < 3072) {                       // live taps
      int band = gid >> 10, j = gid & 1023;
      float v = 0.f;
      if (j < 1023) {
        if (band == 2) {                    // low: 512-tap, right-aligned
          v = (j >= 511) ? irLL[j - 511] : 0.f;
        } else {                            // high/mid: conv(irLH, irH?)
          const float* wb = (band == 0) ? irHH : irHL;
          int lo = j - 511; if (lo < 0) lo = 0;
          int hi = (j < 511) ? j : 511;
          float acc = 0.f;
          for (int i = lo; i <= hi; ++i) acc += irLH[i] * wb[j - i];
          v = acc;
        }
      }
      int entry = band * 1152 + 64 + j;
      short h = f2bf(v);
      whl[entry] = h;
      whl[entry + 4608] = f2bf(v - bf2f(h));
    } else if (gid < 4608) {                // zero edges + band 3
      int z = gid - 3072;
      int entry;
      if (z < 384) {
        int band = z >> 7, r = z & 127;
        entry = band * 1152 + (r < 64 ? r : 1024 + r);
      } else {
        entry = 3 * 1152 + (z - 384);
      }
      whl[entry] = 0;
      whl[entry + 4608] = 0;
    }
  } else if (task == 1) {                   // L0 A-pack: m=oc(16/group), K=k*2+ic (6 live)
    if (gid >= 2048) return;
    int wq = gid >> 9;
    int lane = (gid >> 3) & 63;
    int j = gid & 7;
    int l16 = lane & 15, q = lane >> 4;
    int m = wq * 16 + l16;
    int K = q * 8 + j;
    float val = (K < 6) ? w0[(m * 2 + (K & 1)) * 3 + (K >> 1)] : 0.f;
    ((short*)(ws + OFF_A0))[gid] = f2bf(val);
  } else if (task == 2) {                   // L4 A-pack: rows m=ch (2 live of 16)
    if (gid >= 3072) return;
    int s = gid >> 9;
    int lane = (gid - s * 512) >> 3;
    int j = gid & 7;
    int m = lane & 15, q = lane >> 4;
    int K = s * 32 + q * 8 + j;
    int k = K >> 6, ic = K & 63;
    float val = (m < 2) ? w4[(m * 64 + ic) * 3 + k] : 0.f;
    ((short*)(ws + OFF_A4))[gid] = f2bf(val);
  } else {                                  // A-pack layer l (w1..w3)
    int l = task - 3;
    if (gid >= 12288) return;
    const float* wl = (l == 0) ? w1 : (l == 1) ? w2 : w3;
    int wm = gid / 3072;
    int rem = gid - wm * 3072;
    int s = rem / 512;
    int rem2 = rem - s * 512;
    int lane = rem2 >> 3;
    int j = gid & 7;
    int m = wm * 16 + (lane & 15);               // oc
    int kk = s * 32 + ((lane >> 4) << 3) + j;    // flattened K = k*64+ic
    int k = kk >> 6, ic = kk & 63;
    short* ap = (short*)(ws + OFF_ABF);
    ap[l * 12288 + gid] = f2bf(wl[(m * 64 + ic) * 3 + k]);
  }
}

// ---------------------------------------------------------------- MFMA band FIR
// y[band][T0+16u+n] = sum_j W[j] x[T0+16u+n+j-1022]; shift j'=j+16u folded into
// pre-shifted A tables. Rows m=band*5+u (15 live), cols n=16 time.
// B-frags from 4 parity copies of x (8B-aligned b64 reads).
// 3-chain split: wh*xh + wl*xh + wh*xl (FIR err ~2^-17).
#define FT 320
__global__ __launch_bounds__(256) void k_firm(const float* __restrict__ audio,
                                              float* __restrict__ ws)
{
  __shared__ short xh[4][1360];
  __shared__ short xl[4][1360];
  __shared__ __align__(16) short wt[9216];
  int bc = blockIdx.x, tile = blockIdx.y;
  int t0b = tile * FT;
  int tid = threadIdx.x;
  const uint4* wsrc = (const uint4*)((const short*)(ws + OFF_WHL));
  uint4* wdst = (uint4*)wt;
  for (int i = tid; i < 1152; i += 256) wdst[i] = wsrc[i];   // 9216 shorts = 1152 uint4
  const float* x = audio + bc * NT;
  for (int i = tid; i < 1363; i += 256) {      // unique samples, convert once
    int g = t0b - 1022 + i;
    float v = (g >= 0 && g < NT) ? x[g] * IN_GAIN_F : 0.f;
    short h = f2bf(v);
    short l = f2bf(v - bf2f(h));
#pragma unroll
    for (int c = 0; c < 4; ++c) {
      int idx = i - c;
      if (idx >= 0 && idx < 1360) { xh[c][idx] = h; xl[c][idx] = l; }
    }
  }
  __syncthreads();

  int wave = tid >> 6, lane = tid & 63;
  int q = lane >> 4, l16 = lane & 15;
  int band = (l16 >= 10) ? 2 : (l16 >= 5 ? 1 : 0);
  if (l16 == 15) band = 3;
  int u = l16 - band * 5;                       // band3 -> u=0 (zero taps)
  const short* pAh = wt + band * 1152 + 64 + q * 8 - u * 16;
  const short* pAl = pAh + 4608;
  int c = l16 & 3;
  int xoff = wave * 80 + q * 8 + ((l16 >> 2) << 2);
  const short* pBh = &xh[c][xoff];
  const short* pBl = &xl[c][xoff];
  float4v acc = {0.f, 0.f, 0.f, 0.f};
#pragma unroll 2
  for (int s = 0; s < 34; ++s) {
    short8v ah = *(const short8v*)(pAh + 32 * s);
    short8v al = *(const short8v*)(pAl + 32 * s);
    short4v bh0 = *(const short4v*)(pBh + 32 * s);
    short4v bh1 = *(const short4v*)(pBh + 32 * s + 4);
    short4v bl0 = *(const short4v*)(pBl + 32 * s);
    short4v bl1 = *(const short4v*)(pBl + 32 * s + 4);
    short8v bh = __builtin_shufflevector(bh0, bh1, 0, 1, 2, 3, 4, 5, 6, 7);
    short8v bl = __builtin_shufflevector(bl0, bl1, 0, 1, 2, 3, 4, 5, 6, 7);
    acc = __builtin_amdgcn_mfma_f32_16x16x32_bf16(ah, bh, acc, 0, 0, 0);
    acc = __builtin_amdgcn_mfma_f32_16x16x32_bf16(al, bh, acc, 0, 0, 0);
    acc = __builtin_amdgcn_mfma_f32_16x16x32_bf16(ah, bl, acc, 0, 0, 0);
  }
  int b = bc >> 1, ch = bc & 1;
  float* bands = ws + OFF_BANDS;
#pragma unroll
  for (int r = 0; r < 4; ++r) {
    int m = q * 4 + r;
    if (m < 15) {
      int bnd = (m >= 10) ? 2 : (m >= 5 ? 1 : 0);
      int uu = m - bnd * 5;
      int t = t0b + wave * 80 + uu * 16 + l16;
      if (t < NT) bands[((b * 3 + bnd) * 2 + ch) * NT + t] = acc[r];
    }
  }
}

// ---------------------------------------------------------------- block RMS
__global__ __launch_bounds__(64) void k_rms(float* __restrict__ ws)
{
  int row = blockIdx.x;
  int j = blockIdx.y * 64 + threadIdx.x;
  if (j >= TC) return;
  const float* bnd = ws + OFF_BANDS;
  const float* p0 = bnd + (row * 2 + 0) * NT + j * 64;
  const float* p1 = bnd + (row * 2 + 1) * NT + j * 64;
  float acc = 0.f;
#pragma unroll
  for (int s = 0; s < 64; s += 4) {
    float4 a = *reinterpret_cast<const float4*>(&p0[s]);
    float4 cc = *reinterpret_cast<const float4*>(&p1[s]);
    acc += a.x * a.x + a.y * a.y + a.z * a.z + a.w * a.w
         + cc.x * cc.x + cc.y * cc.y + cc.z * cc.z + cc.w * cc.w;
  }
  ws[OFF_XRMS + row * TC + j] = sqrtf(acc * (0.5f / 64.f) + 1e-7f);
}

// ---------------------------------------------------------------- decaying-max scan
__global__ __launch_bounds__(256) void k_scan(const float* __restrict__ rel_alphas,
                                              float* __restrict__ ws)
{
  __shared__ float sA[TC], sB[TC];
  int row = blockIdx.x;
  int tid = threadIdx.x;
  float kdec = 1.f - rel_alphas[row >> 3];   // reference's repeat() indexing
  float l2k = log2f(kdec);
  const float* xr = ws + OFF_XRMS + row * TC;
  for (int i = tid; i < TC; i += 256) sA[i] = xr[i];
  __syncthreads();
  float* in = sA; float* outp = sB;
  for (int off = 1; off < 2048; off <<= 1) {
    float kp = exp2f(l2k * (float)off);
    for (int i = tid; i < TC; i += 256) {
      float v = in[i];
      if (i >= off) v = fmaxf(v, in[i - off] * kp);
      outp[i] = v;
    }
    __syncthreads();
    float* tmp = in; in = outp; outp = tmp;
  }
  float* env = ws + OFF_ENV + row * TC;
  for (int i = tid; i < TC; i += 256) env[i] = in[i];
}

// ---------------------------------------------------------------- MFMA conv net (+fused gain)
#define PITCH 72
#define SPAN 160
#define TILE 128

__device__ __forceinline__ void mfma_layer(const short* in, short* outb,
    const short* __restrict__ apk, const float* __restrict__ bias,
    const int d, int t0, int wq, int half, int lane)
{
  int quad = lane >> 4, l16 = lane & 15;
  short8v a[6];
#pragma unroll
  for (int s = 0; s < 6; ++s)
    a[s] = *(const short8v*)&apk[(((wq * 6 + s) * 64) + lane) * 8];
  float4 bv = *(const float4*)&bias[wq * 16 + quad * 4];
  float4v acc[5];
#pragma unroll
  for (int n = 0; n < 5; ++n) { acc[n][0] = bv.x; acc[n][1] = bv.y; acc[n][2] = bv.z; acc[n][3] = bv.w; }
#pragma unroll
  for (int s = 0; s < 6; ++s) {
    int k = s >> 1;
    int ic0 = (s & 1) * 32 + quad * 8;
#pragma unroll
    for (int n = 0; n < 5; ++n) {
      int row = (half * 5 + n) * 16 + l16 + (k - 1) * d;
      row = row < 0 ? 0 : (row > SPAN - 1 ? SPAN - 1 : row);
      short8v bf = *(const short8v*)&in[row * PITCH + ic0];
      acc[n] = __builtin_amdgcn_mfma_f32_16x16x32_bf16(a[s], bf, acc[n], 0, 0, 0);
    }
  }
  int ocb = wq * 16 + quad * 4;
#pragma unroll
  for (int n = 0; n < 5; ++n) {
    int p = (half * 5 + n) * 16 + l16;
    int t = t0 - 16 + p;
    bool z = (t < 0) | (t >= NT);
    short4v r;
#pragma unroll
    for (int rg = 0; rg < 4; ++rg)
      r[rg] = f2bft(z ? 0.f : gelus(acc[n][rg]));
    *(short4v*)&outb[p * PITCH + ocb] = r;
  }
}

__global__ __launch_bounds__(512) void k_convnet(
    const float* __restrict__ audio, const float* __restrict__ params,
    const float* __restrict__ kneep,
    const float* __restrict__ b0, const float* __restrict__ b1,
    const float* __restrict__ b2, const float* __restrict__ b3,
    const float* __restrict__ b4, const float* __restrict__ ws,
    float* __restrict__ out)
{
  __shared__ float cmb[2][SPAN];
  __shared__ __align__(16) short bfL0[SPAN][8];
  __shared__ __align__(16) short actA[SPAN * PITCH];
  __shared__ __align__(16) short actB[SPAN * PITCH];
  int tile = blockIdx.x, b = blockIdx.y;
  int t0 = tile * TILE;
  int tid = threadIdx.x;
  int wave = tid >> 6, lane = tid & 63;

  // ---- fused gain+combine for the 160-span (tid<160: one position, both ch)
  if (tid < SPAN) {
    int t = t0 - 16 + tid;
    float c0 = 0.f, c1 = 0.f;
    if (t >= 0 && t < NT) {
      const float* bands = ws + OFF_BANDS;
      const float* env = ws + OFF_ENV;
      float knee = kneep[0];
      float halfk = 0.5f * knee;
      float inv2k = 1.f / (2.f * knee);
      const float scale = (float)(1377.0 / 88199.0);
      float pos = (float)t * scale;
      int i0 = (int)floorf(pos);
      i0 = i0 < 0 ? 0 : (i0 > TC - 2 ? TC - 2 : i0);
      float frac = pos - (float)i0;
      const int tacol[3] = {3, 2, 1};
      const int tbcol[3] = {6, 5, 4};
      const float asl[3] = {1.f, (float)(1.0 - 1.0 / 66.7), (float)(1.0 - 1.0 / 66.7)};
      const float bsl = (float)(1.0 - 1.0 / 4.17);
      const float og[3] = {10.3f, 5.7f, 10.3f};
#pragma unroll
      for (int band = 0; band < 3; ++band) {
        int row = b * 3 + band;
        float e = env[row * TC + i0] * (1.f - frac) + env[row * TC + i0 + 1] * frac;
        float edb = 20.f * log10f(e + 1e-7f);
        float ta = params[b * 7 + tacol[band]];
        float tb = params[b * 7 + tbcol[band]];
        float d1 = edb - ta;
        float gk1 = asl[band] * (d1 + halfk) * (d1 + halfk) * inv2k;
        float ka = (fabsf(d1) <= halfk) ? gk1 : (d1 > halfk ? asl[band] * d1 : 0.f);
        float d2 = tb - edb;
        float gk2 = bsl * (d2 + halfk) * (d2 + halfk) * inv2k;
        float kb = (fabsf(d2) <= halfk) ? gk2 : (d2 > halfk ? bsl * d2 : 0.f);
        float gdb = -ka + kb + og[band];
        gdb = fminf(fmaxf(gdb, -80.f), 40.f);
        float g = exp2f(gdb * 0.16609640474436812f);   // 10^(gdb/20)
        c0 += bands[(row * 2 + 0) * NT + t] * g;
        c1 += bands[(row * 2 + 1) * NT + t] * g;
      }
    }
    cmb[0][tid] = c0;
    cmb[1][tid] = c1;
  }
  __syncthreads();

  // build bfL0[r][j=k*2+ic] = cmb[ic][r-1+k] (bf16), zero-padded
  for (int i = tid; i < SPAN * 8; i += 512) {
    int r = i >> 3, j = i & 7;
    short v = 0;
    if (j < 6) {
      int k = j >> 1, ic = j & 1;
      int src = r - 1 + k;
      if (src >= 0 && src < SPAN) v = f2bf(cmb[ic][src]);
    }
    bfL0[r][j] = v;
  }
  __syncthreads();

  int wq = wave & 3, half = wave >> 2;
  int quad = lane >> 4, l16 = lane & 15;

  // ---- L0 (MFMA): single K=32 step (6 live), B=bfL0
  {
    const short* ap0 = (const short*)(ws + OFF_A0);
    short8v a0 = *(const short8v*)&ap0[(wq * 64 + lane) * 8];
    float4 bv = *(const float4*)&b0[wq * 16 + quad * 4];
    float4v acc[5];
#pragma unroll
    for (int n = 0; n < 5; ++n) { acc[n][0] = bv.x; acc[n][1] = bv.y; acc[n][2] = bv.z; acc[n][3] = bv.w; }
    short8v zf = {0, 0, 0, 0, 0, 0, 0, 0};
#pragma unroll
    for (int n = 0; n < 5; ++n) {
      int row = (half * 5 + n) * 16 + l16;
      short8v bf = (quad == 0) ? *(const short8v*)&bfL0[row][0] : zf;
      acc[n] = __builtin_amdgcn_mfma_f32_16x16x32_bf16(a0, bf, acc[n], 0, 0, 0);
    }
    int ocb = wq * 16 + quad * 4;
#pragma unroll
    for (int n = 0; n < 5; ++n) {
      int p = (half * 5 + n) * 16 + l16;
      int t = t0 - 16 + p;
      bool z = (t < 0) | (t >= NT);
      short4v r;
#pragma unroll
      for (int rg = 0; rg < 4; ++rg)
        r[rg] = f2bft(z ? 0.f : gelus(acc[n][rg]));
      *(short4v*)&actA[p * PITCH + ocb] = r;
    }
  }
  __syncthreads();

  const short* apk = (const short*)(ws + OFF_ABF);
  mfma_layer(actA, actB, apk,          b1, 2, t0, wq, half, lane);
  __syncthreads();
  mfma_layer(actB, actA, apk + 12288,  b2, 4, t0, wq, half, lane);
  __syncthreads();
  mfma_layer(actA, actB, apk + 24576,  b3, 8, t0, wq, half, lane);
  __syncthreads();

  // ---- L4 (MFMA): rows m=ch (2 live); + final mix
  {
    const short* ap4 = (const short*)(ws + OFF_A4);
    float4v acc = {0.f, 0.f, 0.f, 0.f};
    if (quad == 0) { acc[0] = b4[0]; acc[1] = b4[1]; }
#pragma unroll
    for (int s = 0; s < 6; ++s) {
      short8v a4 = *(const short8v*)&ap4[(s * 64 + lane) * 8];
      int kt = s >> 1;
      int ic0 = (s & 1) * 32 + quad * 8;
      int row = 16 + wave * 16 + l16 + kt - 1;
      short8v bf = *(const short8v*)&actB[row * PITCH + ic0];
      acc = __builtin_amdgcn_mfma_f32_16x16x32_bf16(a4, bf, acc, 0, 0, 0);
    }
    if (quad == 0) {
      int t = t0 + wave * 16 + l16;
      if (t < NT) {
        float amt = params[b * 7];
#pragma unroll
        for (int r = 0; r < 2; ++r) {
          float aud = audio[(b * 2 + r) * NT + t];
          out[(b * 2 + r) * NT + t] =
              (1.f - amt) * aud + amt * (cmb[r][16 + wave * 16 + l16] + acc[r]);
        }
      }
    }
  }
}

// ----------------------------------------------------------------
extern "C" void kernel_launch(void* const* d_in, const int* in_sizes, int n_in,
                              void* d_out, int out_size, void* d_ws, size_t ws_size,
                              hipStream_t stream)
{
  (void)in_sizes; (void)n_in; (void)out_size; (void)ws_size;
  const float* audio = (const float*)d_in[0];
  const float* params = (const float*)d_in[1];
  const float* rel   = (const float*)d_in[2];
  const float* knee  = (const float*)d_in[3];
  const float* irLL  = (const float*)d_in[4];
  const float* irLH  = (const float*)d_in[5];
  const float* irHL  = (const float*)d_in[6];
  const float* irHH  = (const float*)d_in[7];
  const float* w0 = (const float*)d_in[8];  const float* b0 = (const float*)d_in[9];
  const float* w1 = (const float*)d_in[10]; const float* b1 = (const float*)d_in[11];
  const float* w2 = (const float*)d_in[12]; const float* b2 = (const float*)d_in[13];
  const float* w3 = (const float*)d_in[14]; const float* b3 = (const float*)d_in[15];
  const float* w4 = (const float*)d_in[16]; const float* b4 = (const float*)d_in[17];
  float* out = (float*)d_out;
  float* ws  = (float*)d_ws;

  hipLaunchKernelGGL(k_prep, dim3(48, 6), dim3(256), 0, stream,
                     irLL, irLH, irHL, irHH, w0, w1, w2, w3, w4, ws);
  hipLaunchKernelGGL(k_firm, dim3(16, 276), dim3(256), 0, stream, audio, ws);
  hipLaunchKernelGGL(k_rms, dim3(24, 22), dim3(64), 0, stream, ws);
  hipLaunchKernelGGL(k_scan, dim3(24), dim3(256), 0, stream, rel, ws);
  hipLaunchKernelGGL(k_convnet, dim3(690, 8), dim3(512), 0, stream,
                     audio, params, knee, b0, b1, b2, b3, b4, ws, out);
}